// Round 21
// baseline (2990.276 us; speedup 1.0000x reference)
//
#include <hip/hip_runtime.h>
#include <hip/hip_bf16.h>
#include <math.h>

#define BB 4
#define TT 4096
#define CC 1024
#define HH 16
#define NN 64
#define BT (BB*TT)            // 16384 rows
#define EPS_GN 6.4e-4f        // 1e-5 * 8^2
#define TMAX (TT-1)
#define LCH 64                // chunk length
#define STR 68                // padded LDS row stride (multiple of 4 -> b128)
#define STR3 20               // quarter-width padded stride (16+4)

typedef __attribute__((ext_vector_type(8))) short bf16x8;
typedef __attribute__((ext_vector_type(4))) float f32x4;

__device__ __forceinline__ float sigmoidf_(float x) {
    return 1.0f / (1.0f + expf(-x));
}

__device__ __forceinline__ float waveReduceSum(float v) {
    #pragma unroll
    for (int off = 32; off > 0; off >>= 1)
        v += __shfl_xor(v, off, 64);
    return v;
}

__device__ __forceinline__ unsigned short f2bf(float f) {
    unsigned u = __float_as_uint(f);
    u += 0x7FFFu + ((u >> 16) & 1u);
    return (unsigned short)(u >> 16);
}
__device__ __forceinline__ float bf2f(unsigned short h) {
    return __uint_as_float(((unsigned)h) << 16);
}

__device__ __forceinline__ void gll16(const unsigned short* g, unsigned short* l) {
    __builtin_amdgcn_global_load_lds(
        (__attribute__((address_space(1))) void*)(g),
        (__attribute__((address_space(3))) void*)(l), 16, 0, 0);
}

// acc[r][c] += sum_k A(tr+r,k)*B(tc+c,k); element A(i,k)=A[i*SA0+k*SA1].
template<int SA0,int SA1,int SB0,int SB1>
__device__ __forceinline__ void gemm64(const float* __restrict__ A,
                                       const float* __restrict__ B,
                                       float acc[4][4], int tr, int tc) {
    #pragma unroll 2
    for (int kx = 0; kx < 64; kx += 4) {
        float a_[4][4];   // [r][kk]
        if (SA0 == 1) {
            #pragma unroll
            for (int kk = 0; kk < 4; kk++) {
                float4 t = *(const float4*)&A[tr + (kx + kk) * SA1];
                a_[0][kk] = t.x; a_[1][kk] = t.y; a_[2][kk] = t.z; a_[3][kk] = t.w;
            }
        } else {
            #pragma unroll
            for (int r = 0; r < 4; r++) {
                float4 t = *(const float4*)&A[(tr + r) * SA0 + kx];
                a_[r][0] = t.x; a_[r][1] = t.y; a_[r][2] = t.z; a_[r][3] = t.w;
            }
        }
        float b_[4][4];   // [cq][kk]
        if (SB0 == 1) {
            #pragma unroll
            for (int kk = 0; kk < 4; kk++) {
                float4 t = *(const float4*)&B[tc + (kx + kk) * SB1];
                b_[0][kk] = t.x; b_[1][kk] = t.y; b_[2][kk] = t.z; b_[3][kk] = t.w;
            }
        } else {
            #pragma unroll
            for (int cq = 0; cq < 4; cq++) {
                float4 t = *(const float4*)&B[(tc + cq) * SB0 + kx];
                b_[cq][0] = t.x; b_[cq][1] = t.y; b_[cq][2] = t.z; b_[cq][3] = t.w;
            }
        }
        #pragma unroll
        for (int r = 0; r < 4; r++)
            #pragma unroll
            for (int cq = 0; cq < 4; cq++)
                #pragma unroll
                for (int kk = 0; kk < 4; kk++)
                    acc[r][cq] = fmaf(a_[r][kk], b_[cq][kk], acc[r][cq]);
    }
}

// ---------------------------------------------------------------------------
// Fused mix+split for ALL SIX mixes: reads x (+prev) ONCE, emits 6 hi/lo pairs.
// ---------------------------------------------------------------------------
__global__ __launch_bounds__(256) void conv_split_x6(
    const float* __restrict__ X,
    const float* __restrict__ mr, const float* __restrict__ mk,
    const float* __restrict__ mv, const float* __restrict__ mw,
    const float* __restrict__ ma, const float* __restrict__ mg,
    unsigned short* __restrict__ rH, unsigned short* __restrict__ rL,
    unsigned short* __restrict__ kH, unsigned short* __restrict__ kL,
    unsigned short* __restrict__ vH, unsigned short* __restrict__ vL,
    unsigned short* __restrict__ wH, unsigned short* __restrict__ wL,
    unsigned short* __restrict__ aH, unsigned short* __restrict__ aL,
    unsigned short* __restrict__ gH, unsigned short* __restrict__ gL)
{
    int g = blockIdx.x * 256 + threadIdx.x;
    int m = g >> 7;
    int k = (g & 127) * 8;
    const float* px = X + (size_t)m * CC + k;
    float xv8[8], pv[8];
    {
        float4 x0 = *(const float4*)px;
        float4 x1 = *(const float4*)(px + 4);
        xv8[0]=x0.x; xv8[1]=x0.y; xv8[2]=x0.z; xv8[3]=x0.w;
        xv8[4]=x1.x; xv8[5]=x1.y; xv8[6]=x1.z; xv8[7]=x1.w;
    }
    if ((m & (TT - 1)) == 0) {
        #pragma unroll
        for (int j = 0; j < 8; j++) pv[j] = 0.f;
    } else {
        float4 p0 = *(const float4*)(px - CC);
        float4 p1 = *(const float4*)(px - CC + 4);
        pv[0]=p0.x; pv[1]=p0.y; pv[2]=p0.z; pv[3]=p0.w;
        pv[4]=p1.x; pv[5]=p1.y; pv[6]=p1.z; pv[7]=p1.w;
    }
    const float* mixes[6] = {mr, mk, mv, mw, ma, mg};
    unsigned short* His[6] = {rH, kH, vH, wH, aH, gH};
    unsigned short* Los[6] = {rL, kL, vL, wL, aL, gL};
    for (int s = 0; s < 6; s++) {
        float4 m0 = *(const float4*)(mixes[s] + k);
        float4 m1 = *(const float4*)(mixes[s] + k + 4);
        float mv8[8] = {m0.x,m0.y,m0.z,m0.w,m1.x,m1.y,m1.z,m1.w};
        unsigned short hi[8], lo[8];
        #pragma unroll
        for (int j = 0; j < 8; j++) {
            float a = xv8[j] + (pv[j] - xv8[j]) * mv8[j];
            hi[j] = f2bf(a);
            lo[j] = f2bf(a - bf2f(hi[j]));
        }
        uint4 H, L;
        H.x = (unsigned)hi[0] | ((unsigned)hi[1] << 16);
        H.y = (unsigned)hi[2] | ((unsigned)hi[3] << 16);
        H.z = (unsigned)hi[4] | ((unsigned)hi[5] << 16);
        H.w = (unsigned)hi[6] | ((unsigned)hi[7] << 16);
        L.x = (unsigned)lo[0] | ((unsigned)lo[1] << 16);
        L.y = (unsigned)lo[2] | ((unsigned)lo[3] << 16);
        L.z = (unsigned)lo[4] | ((unsigned)lo[5] << 16);
        L.w = (unsigned)lo[6] | ((unsigned)lo[7] << 16);
        *(uint4*)(His[s] + (size_t)g * 8) = H;
        *(uint4*)(Los[s] + (size_t)g * 8) = L;
    }
}

// ---------------------------------------------------------------------------
// All 4 big weights -> 4-slot split-bf16 buffer. blockIdx.y selects W & slot.
// ---------------------------------------------------------------------------
__global__ __launch_bounds__(256) void conv_w4(
    const float* __restrict__ Wr, const float* __restrict__ Wk,
    const float* __restrict__ Wv, const float* __restrict__ Wo,
    unsigned short* __restrict__ Hi, unsigned short* __restrict__ Lo)
{
    int g = blockIdx.x * 256 + threadIdx.x;      // 0 .. CC*CC/8-1
    int y = blockIdx.y;
    const float* W = (y == 0) ? Wr : (y == 1) ? Wk : (y == 2) ? Wv : Wo;
    size_t doff = (size_t)y * CC * CC;
    int m = g >> 7;
    int k = (g & 127) * 8;
    const float* px = W + (size_t)m * CC + k;
    float a[8];
    {
        float4 x0 = *(const float4*)px;
        float4 x1 = *(const float4*)(px + 4);
        a[0]=x0.x; a[1]=x0.y; a[2]=x0.z; a[3]=x0.w;
        a[4]=x1.x; a[5]=x1.y; a[6]=x1.z; a[7]=x1.w;
    }
    unsigned short hi[8], lo[8];
    #pragma unroll
    for (int j = 0; j < 8; j++) {
        hi[j] = f2bf(a[j]);
        lo[j] = f2bf(a[j] - bf2f(hi[j]));
    }
    uint4 H, L;
    H.x = (unsigned)hi[0] | ((unsigned)hi[1] << 16);
    H.y = (unsigned)hi[2] | ((unsigned)hi[3] << 16);
    H.z = (unsigned)hi[4] | ((unsigned)hi[5] << 16);
    H.w = (unsigned)hi[6] | ((unsigned)hi[7] << 16);
    L.x = (unsigned)lo[0] | ((unsigned)lo[1] << 16);
    L.y = (unsigned)lo[2] | ((unsigned)lo[3] << 16);
    L.z = (unsigned)lo[4] | ((unsigned)lo[5] << 16);
    L.w = (unsigned)lo[6] | ((unsigned)lo[7] << 16);
    *(uint4*)(Hi + doff + (size_t)g * 8) = H;
    *(uint4*)(Lo + doff + (size_t)g * 8) = L;
}

// ---------------------------------------------------------------------------
// Stage-1 weight transpose+split, 4 slices in one launch (blockIdx.y):
// W (1024, N) n-contig -> (Npad, 1024) k-contig hi/lo, rows >= N zero.
// ---------------------------------------------------------------------------
__global__ __launch_bounds__(256) void conv_w1y(
    const float* __restrict__ w1, const float* __restrict__ a1,
    const float* __restrict__ v1, const float* __restrict__ g1,
    unsigned short* __restrict__ w1th, unsigned short* __restrict__ w1tl,
    unsigned short* __restrict__ a1th, unsigned short* __restrict__ a1tl,
    unsigned short* __restrict__ v1th, unsigned short* __restrict__ v1tl,
    unsigned short* __restrict__ g1th, unsigned short* __restrict__ g1tl)
{
    const int y = blockIdx.y;
    const float* W = (y == 0) ? w1 : (y == 1) ? a1 : (y == 2) ? v1 : g1;
    unsigned short* Hi = (y == 0) ? w1th : (y == 1) ? a1th : (y == 2) ? v1th : g1th;
    unsigned short* Lo = (y == 0) ? w1tl : (y == 1) ? a1tl : (y == 2) ? v1tl : g1tl;
    const int N    = (y == 2) ? 32 : (y == 3) ? 160 : 64;
    const int Npad = (y == 3) ? 192 : 64;
    int idx = blockIdx.x * 256 + threadIdx.x;
    if (idx >= Npad * 128) return;
    int n = idx >> 7, k0 = (idx & 127) * 8;
    unsigned short h8[8], l8[8];
    #pragma unroll
    for (int j = 0; j < 8; j++) {
        int k = k0 + j;
        float v = (n < N) ? W[(size_t)k * N + n] : 0.f;
        h8[j] = f2bf(v);
        l8[j] = f2bf(v - bf2f(h8[j]));
    }
    uint4 H, L;
    H.x = (unsigned)h8[0] | ((unsigned)h8[1] << 16);
    H.y = (unsigned)h8[2] | ((unsigned)h8[3] << 16);
    H.z = (unsigned)h8[4] | ((unsigned)h8[5] << 16);
    H.w = (unsigned)h8[6] | ((unsigned)h8[7] << 16);
    L.x = (unsigned)l8[0] | ((unsigned)l8[1] << 16);
    L.y = (unsigned)l8[2] | ((unsigned)l8[3] << 16);
    L.z = (unsigned)l8[4] | ((unsigned)l8[5] << 16);
    L.w = (unsigned)l8[6] | ((unsigned)l8[7] << 16);
    *(uint4*)(Hi + (size_t)n * CC + k0) = H;
    *(uint4*)(Lo + (size_t)n * CC + k0) = L;
}

// ---------------------------------------------------------------------------
// Stage-2 weight transpose+split, 4 slices in one launch (blockIdx.y):
// W (K,CC) n-contig -> (CC,Kp) k-contig hi/lo, cols >= K zero.
// ---------------------------------------------------------------------------
__global__ __launch_bounds__(256) void conv_w2y(
    const float* __restrict__ w2, const float* __restrict__ a2,
    const float* __restrict__ v2, const float* __restrict__ g2,
    unsigned short* __restrict__ w2th, unsigned short* __restrict__ w2tl,
    unsigned short* __restrict__ a2th, unsigned short* __restrict__ a2tl,
    unsigned short* __restrict__ v2th, unsigned short* __restrict__ v2tl,
    unsigned short* __restrict__ g2th, unsigned short* __restrict__ g2tl)
{
    const int y = blockIdx.y;
    const float* W = (y == 0) ? w2 : (y == 1) ? a2 : (y == 2) ? v2 : g2;
    unsigned short* Hi = (y == 0) ? w2th : (y == 1) ? a2th : (y == 2) ? v2th : g2th;
    unsigned short* Lo = (y == 0) ? w2tl : (y == 1) ? a2tl : (y == 2) ? v2tl : g2tl;
    const int K  = (y == 2) ? 32 : (y == 3) ? 160 : 64;
    const int Kp = (y == 3) ? 192 : 64;
    int idx = blockIdx.x * 256 + threadIdx.x;
    int nk8 = Kp >> 3;
    if (idx >= CC * nk8) return;
    int n = idx / nk8, k0 = (idx - n * nk8) * 8;
    unsigned short h8[8], l8[8];
    #pragma unroll
    for (int j = 0; j < 8; j++) {
        int k = k0 + j;
        float v = (k < K) ? W[(size_t)k * CC + n] : 0.f;
        h8[j] = f2bf(v);
        l8[j] = f2bf(v - bf2f(h8[j]));
    }
    uint4 H, L;
    H.x = (unsigned)h8[0] | ((unsigned)h8[1] << 16);
    H.y = (unsigned)h8[2] | ((unsigned)h8[3] << 16);
    H.z = (unsigned)h8[4] | ((unsigned)h8[5] << 16);
    H.w = (unsigned)h8[6] | ((unsigned)h8[7] << 16);
    L.x = (unsigned)l8[0] | ((unsigned)l8[1] << 16);
    L.y = (unsigned)l8[2] | ((unsigned)l8[3] << 16);
    L.z = (unsigned)l8[4] | ((unsigned)l8[5] << 16);
    L.w = (unsigned)l8[6] | ((unsigned)l8[7] << 16);
    *(uint4*)(Hi + (size_t)n * Kp + k0) = H;
    *(uint4*)(Lo + (size_t)n * Kp + k0) = L;
}

// ---------------------------------------------------------------------------
// Split-bf16 MFMA GEMM v3 (unchanged — passed)
// ---------------------------------------------------------------------------
__global__ __launch_bounds__(256, 3) void gemm_split_bf16(
    const unsigned short* __restrict__ A0h, const unsigned short* __restrict__ A0l,
    const unsigned short* __restrict__ A1h, const unsigned short* __restrict__ A1l,
    const unsigned short* __restrict__ A2h, const unsigned short* __restrict__ A2l,
    const unsigned short* __restrict__ W4h, const unsigned short* __restrict__ W4l,
    float* __restrict__ O0, float* __restrict__ O1, float* __restrict__ O2,
    int wbase)
{
    __shared__ __align__(16) unsigned short lds[4][128 * 32];   // 32 KB
    const int sel = blockIdx.y;
    const unsigned short* Ah = (sel == 0) ? A0h : (sel == 1) ? A1h : A2h;
    const unsigned short* Al = (sel == 0) ? A0l : (sel == 1) ? A1l : A2l;
    float* Out = (sel == 0) ? O0 : (sel == 1) ? O1 : O2;
    const unsigned short* Bh = W4h + (size_t)(wbase + sel) * CC * CC;
    const unsigned short* Bl = W4l + (size_t)(wbase + sel) * CC * CC;
    const int tid = threadIdx.x, lane = tid & 63, wave = tid >> 6;
    const int wm = (wave >> 1) * 64, wn = (wave & 1) * 64;
    const int wg = blockIdx.x;
    const int xcd = wg & 7;
    const int j = wg >> 3;
    const int m0 = ((j >> 3) * 8 + xcd) * 128;
    const int n0 = (j & 7) * 128;

    f32x4 acc[4][4];
    #pragma unroll
    for (int i = 0; i < 4; i++)
        #pragma unroll
        for (int jj = 0; jj < 4; jj++)
            acc[i][jj] = (f32x4){0.f, 0.f, 0.f, 0.f};

    for (int k0 = 0; k0 < CC; k0 += 32) {
        #pragma unroll
        for (int p = 0; p < 4; p++) {
            const unsigned short* sbase = (p == 0) ? Ah : (p == 1) ? Al
                                        : (p == 2) ? Bh : Bl;
            const int rbase = (p < 2) ? m0 : n0;
            #pragma unroll
            for (int i = 0; i < 2; i++) {
                int slot = i * 256 + wave * 64 + lane;   // 0..511
                int row = slot >> 2, gsl = slot & 3;
                const unsigned short* src = sbase
                    + (size_t)(rbase + row) * CC + k0 + ((gsl ^ (row & 3)) * 8);
                gll16(src, &lds[p][(size_t)(i * 256 + wave * 64) * 8]);
            }
        }
        __syncthreads();

        const int gk = lane >> 4;
        bf16x8 bhf[4], blf[4];
        #pragma unroll
        for (int nt = 0; nt < 4; nt++) {
            int col = wn + nt * 16 + (lane & 15);
            int el = col * 32 + ((gk ^ (col & 3)) * 8);
            bhf[nt] = *(const bf16x8*)&lds[2][el];
            blf[nt] = *(const bf16x8*)&lds[3][el];
        }
        #pragma unroll
        for (int mt = 0; mt < 4; mt++) {
            int row = wm + mt * 16 + (lane & 15);
            int el = row * 32 + ((gk ^ (row & 3)) * 8);
            bf16x8 ahf = *(const bf16x8*)&lds[0][el];
            bf16x8 alf = *(const bf16x8*)&lds[1][el];
            #pragma unroll
            for (int nt = 0; nt < 4; nt++) {
                acc[mt][nt] = __builtin_amdgcn_mfma_f32_16x16x32_bf16(
                    ahf, bhf[nt], acc[mt][nt], 0, 0, 0);
                acc[mt][nt] = __builtin_amdgcn_mfma_f32_16x16x32_bf16(
                    alf, bhf[nt], acc[mt][nt], 0, 0, 0);
                acc[mt][nt] = __builtin_amdgcn_mfma_f32_16x16x32_bf16(
                    ahf, blf[nt], acc[mt][nt], 0, 0, 0);
            }
        }
        __syncthreads();
    }
    #pragma unroll
    for (int mt = 0; mt < 4; mt++)
        #pragma unroll
        for (int nt = 0; nt < 4; nt++) {
            int col = n0 + wn + nt * 16 + (lane & 15);
            #pragma unroll
            for (int r = 0; r < 4; r++) {
                int row = m0 + wm + mt * 16 + (lane >> 4) * 4 + r;
                Out[(size_t)row * CC + col] = acc[mt][nt][r];
            }
        }
}

// ---------------------------------------------------------------------------
// LoRA stage-1 on MFMA (unchanged — passed)
// ---------------------------------------------------------------------------
__global__ __launch_bounds__(256, 3) void lora1_mfma(
    const unsigned short* __restrict__ xwh, const unsigned short* __restrict__ xwl,
    const unsigned short* __restrict__ xah, const unsigned short* __restrict__ xal,
    const unsigned short* __restrict__ xvh, const unsigned short* __restrict__ xvl,
    const unsigned short* __restrict__ xgh, const unsigned short* __restrict__ xgl,
    const unsigned short* __restrict__ w1th, const unsigned short* __restrict__ w1tl,
    const unsigned short* __restrict__ a1th, const unsigned short* __restrict__ a1tl,
    const unsigned short* __restrict__ v1th, const unsigned short* __restrict__ v1tl,
    const unsigned short* __restrict__ g1th, const unsigned short* __restrict__ g1tl,
    unsigned short* __restrict__ awh, unsigned short* __restrict__ awl,
    unsigned short* __restrict__ aah, unsigned short* __restrict__ aal,
    unsigned short* __restrict__ avh, unsigned short* __restrict__ avl,
    unsigned short* __restrict__ agh, unsigned short* __restrict__ agl)
{
    __shared__ __align__(16) unsigned short lds[12288];   // 24 KB
    const int y = blockIdx.y;
    const unsigned short *Ah, *Al, *Bh, *Bl;
    unsigned short *Oh, *Ol;
    int n0, epi, Kp;
    if (y == 0)      { Ah=xwh; Al=xwl; Bh=w1th; Bl=w1tl; Oh=awh; Ol=awl; n0=0; epi=1; Kp=64; }
    else if (y == 1) { Ah=xah; Al=xal; Bh=a1th; Bl=a1tl; Oh=aah; Ol=aal; n0=0; epi=0; Kp=64; }
    else if (y == 2) { Ah=xvh; Al=xvl; Bh=v1th; Bl=v1tl; Oh=avh; Ol=avl; n0=0; epi=0; Kp=64; }
    else             { Ah=xgh; Al=xgl; Bh=g1th + (size_t)(y-3)*64*CC;
                       Bl=g1tl + (size_t)(y-3)*64*CC; Oh=agh; Ol=agl;
                       n0=(y-3)*64; epi=2; Kp=192; }

    const int tid = threadIdx.x, lane = tid & 63, wave = tid >> 6;
    const int wm = (wave >> 1) * 64, wn = (wave & 1) * 32;
    const int m0 = blockIdx.x * 128;

    f32x4 acc[4][2];
    #pragma unroll
    for (int i = 0; i < 4; i++)
        #pragma unroll
        for (int jj = 0; jj < 2; jj++)
            acc[i][jj] = (f32x4){0.f, 0.f, 0.f, 0.f};

    for (int k0 = 0; k0 < CC; k0 += 32) {
        #pragma unroll
        for (int p = 0; p < 2; p++) {
            const unsigned short* sbase = (p == 0) ? Ah : Al;
            #pragma unroll
            for (int i = 0; i < 2; i++) {
                int slot = i * 256 + wave * 64 + lane;
                int row = slot >> 2, gsl = slot & 3;
                const unsigned short* src = sbase
                    + (size_t)(m0 + row) * CC + k0 + ((gsl ^ (row & 3)) * 8);
                gll16(src, &lds[(size_t)(p * 4096) + (size_t)(i * 256 + wave * 64) * 8]);
            }
        }
        #pragma unroll
        for (int p = 0; p < 2; p++) {
            const unsigned short* sbase = (p == 0) ? Bh : Bl;
            int slot = wave * 64 + lane;
            int row = slot >> 2, gsl = slot & 3;
            const unsigned short* src = sbase
                + (size_t)row * CC + k0 + ((gsl ^ (row & 3)) * 8);
            gll16(src, &lds[(size_t)(8192 + p * 2048) + (size_t)slot * 8]);
        }
        __syncthreads();

        const int gk = lane >> 4;
        bf16x8 bhf[2], blf[2];
        #pragma unroll
        for (int nt = 0; nt < 2; nt++) {
            int col = wn + nt * 16 + (lane & 15);
            int el = col * 32 + ((gk ^ (col & 3)) * 8);
            bhf[nt] = *(const bf16x8*)&lds[8192 + el];
            blf[nt] = *(const bf16x8*)&lds[10240 + el];
        }
        #pragma unroll
        for (int mt = 0; mt < 4; mt++) {
            int row = wm + mt * 16 + (lane & 15);
            int el = row * 32 + ((gk ^ (row & 3)) * 8);
            bf16x8 ahf = *(const bf16x8*)&lds[el];
            bf16x8 alf = *(const bf16x8*)&lds[4096 + el];
            #pragma unroll
            for (int nt = 0; nt < 2; nt++) {
                acc[mt][nt] = __builtin_amdgcn_mfma_f32_16x16x32_bf16(
                    ahf, bhf[nt], acc[mt][nt], 0, 0, 0);
                acc[mt][nt] = __builtin_amdgcn_mfma_f32_16x16x32_bf16(
                    alf, bhf[nt], acc[mt][nt], 0, 0, 0);
                acc[mt][nt] = __builtin_amdgcn_mfma_f32_16x16x32_bf16(
                    ahf, blf[nt], acc[mt][nt], 0, 0, 0);
            }
        }
        __syncthreads();
    }
    #pragma unroll
    for (int mt = 0; mt < 4; mt++)
        #pragma unroll
        for (int nt = 0; nt < 2; nt++) {
            int col = n0 + wn + nt * 16 + (lane & 15);
            #pragma unroll
            for (int r = 0; r < 4; r++) {
                int row = m0 + wm + mt * 16 + (lane >> 4) * 4 + r;
                float v = acc[mt][nt][r];
                if (epi == 1) v = tanhf(v);
                else if (epi == 2) v = sigmoidf_(v);
                unsigned short h = f2bf(v);
                size_t off = (size_t)row * Kp + col;
                Oh[off] = h;
                Ol[off] = f2bf(v - bf2f(h));
            }
        }
}

// ---------------------------------------------------------------------------
// LoRA stage-2 on MFMA (unchanged — passed)
// ---------------------------------------------------------------------------
__global__ __launch_bounds__(256, 3) void lora2_mfma(
    const unsigned short* __restrict__ awh, const unsigned short* __restrict__ awl,
    const unsigned short* __restrict__ aah, const unsigned short* __restrict__ aal,
    const unsigned short* __restrict__ avh, const unsigned short* __restrict__ avl,
    const unsigned short* __restrict__ agh, const unsigned short* __restrict__ agl,
    const unsigned short* __restrict__ w2h, const unsigned short* __restrict__ w2l,
    const unsigned short* __restrict__ a2h, const unsigned short* __restrict__ a2l,
    const unsigned short* __restrict__ v2h, const unsigned short* __restrict__ v2l,
    const unsigned short* __restrict__ g2h, const unsigned short* __restrict__ g2l,
    const float* __restrict__ w0, const float* __restrict__ a0v,
    const float* __restrict__ v0v, const float* __restrict__ v_first,
    float* __restrict__ decb, float* __restrict__ ab,
    float* __restrict__ vbuf, float* __restrict__ gb)
{
    __shared__ __align__(16) unsigned short lds[24576];   // 48 KB
    const int z = blockIdx.z;
    const unsigned short *Ah, *Al, *Bh, *Bl; int Kp;
    if (z == 0)      { Ah = awh; Al = awl; Bh = w2h; Bl = w2l; Kp = 64;  }
    else if (z == 1) { Ah = aah; Al = aal; Bh = a2h; Bl = a2l; Kp = 64;  }
    else if (z == 2) { Ah = avh; Al = avl; Bh = v2h; Bl = v2l; Kp = 64;  }
    else             { Ah = agh; Al = agl; Bh = g2h; Bl = g2l; Kp = 192; }

    const int tid = threadIdx.x, lane = tid & 63, wave = tid >> 6;
    const int wm = (wave >> 1) * 64, wn = (wave & 1) * 32;
    const int m0 = blockIdx.x * 128, n0 = blockIdx.y * 64;

    f32x4 acc[4][2];
    #pragma unroll
    for (int i = 0; i < 4; i++)
        #pragma unroll
        for (int jj = 0; jj < 2; jj++)
            acc[i][jj] = (f32x4){0.f, 0.f, 0.f, 0.f};

    for (int k0 = 0; k0 < Kp; k0 += 64) {
        #pragma unroll
        for (int p = 0; p < 2; p++) {
            const unsigned short* sbase = (p == 0) ? Ah : Al;
            #pragma unroll
            for (int i = 0; i < 4; i++) {
                int slot = i * 256 + wave * 64 + lane;
                int row = slot >> 3, gsl = slot & 7;
                const unsigned short* src = sbase
                    + (size_t)(m0 + row) * Kp + k0 + ((gsl ^ (row & 7)) * 8);
                gll16(src, &lds[(size_t)(p * 8192) + (size_t)(i * 256 + wave * 64) * 8]);
            }
        }
        #pragma unroll
        for (int p = 0; p < 2; p++) {
            const unsigned short* sbase = (p == 0) ? Bh : Bl;
            #pragma unroll
            for (int i = 0; i < 2; i++) {
                int slot = i * 256 + wave * 64 + lane;
                int row = slot >> 3, gsl = slot & 7;
                const unsigned short* src = sbase
                    + (size_t)(n0 + row) * Kp + k0 + ((gsl ^ (row & 7)) * 8);
                gll16(src, &lds[(size_t)(16384 + p * 4096) + (size_t)(i * 256 + wave * 64) * 8]);
            }
        }
        __syncthreads();

        #pragma unroll
        for (int ks = 0; ks < 2; ks++) {
            bf16x8 bhf[2], blf[2];
            #pragma unroll
            for (int nt = 0; nt < 2; nt++) {
                int col = wn + nt * 16 + (lane & 15);
                int gk = ks * 4 + (lane >> 4);
                int el = col * 64 + ((gk ^ (col & 7)) * 8);
                bhf[nt] = *(const bf16x8*)&lds[16384 + el];
                blf[nt] = *(const bf16x8*)&lds[20480 + el];
            }
            #pragma unroll
            for (int mt = 0; mt < 4; mt++) {
                int row = wm + mt * 16 + (lane & 15);
                int gk = ks * 4 + (lane >> 4);
                int el = row * 64 + ((gk ^ (row & 7)) * 8);
                bf16x8 ahf = *(const bf16x8*)&lds[el];
                bf16x8 alf = *(const bf16x8*)&lds[8192 + el];
                #pragma unroll
                for (int nt = 0; nt < 2; nt++) {
                    acc[mt][nt] = __builtin_amdgcn_mfma_f32_16x16x32_bf16(
                        ahf, bhf[nt], acc[mt][nt], 0, 0, 0);
                    acc[mt][nt] = __builtin_amdgcn_mfma_f32_16x16x32_bf16(
                        alf, bhf[nt], acc[mt][nt], 0, 0, 0);
                    acc[mt][nt] = __builtin_amdgcn_mfma_f32_16x16x32_bf16(
                        ahf, blf[nt], acc[mt][nt], 0, 0, 0);
                }
            }
        }
        __syncthreads();
    }
    float* cf = (float*)&lds[0];
    #pragma unroll
    for (int mt = 0; mt < 4; mt++)
        #pragma unroll
        for (int nt = 0; nt < 2; nt++)
            #pragma unroll
            for (int r = 0; r < 4; r++) {
                int row = wm + mt * 16 + (lane >> 4) * 4 + r;
                int col = wn + nt * 16 + (lane & 15);
                cf[row * 68 + col] = acc[mt][nt][r];
            }
    __syncthreads();
    #pragma unroll
    for (int i = 0; i < 8; i++) {
        int idx = tid + 256 * i;
        int row = idx >> 4, c4 = (idx & 15) * 4;
        float4 v = *(float4*)&cf[row * 68 + c4];
        int gm = m0 + row;
        int c = n0 + c4;
        size_t off = (size_t)gm * CC + c;
        if (z == 0) {
            float4 w0q = *(const float4*)(w0 + c);
            float4 o;
            o.x = expf(-expf(-log1pf(expf(-(w0q.x + v.x))) - 0.5f));
            o.y = expf(-expf(-log1pf(expf(-(w0q.y + v.y))) - 0.5f));
            o.z = expf(-expf(-log1pf(expf(-(w0q.z + v.z))) - 0.5f));
            o.w = expf(-expf(-log1pf(expf(-(w0q.w + v.w))) - 0.5f));
            *(float4*)&decb[off] = o;
        } else if (z == 1) {
            float4 a0q = *(const float4*)(a0v + c);
            float4 o;
            o.x = sigmoidf_(a0q.x + v.x);
            o.y = sigmoidf_(a0q.y + v.y);
            o.z = sigmoidf_(a0q.z + v.z);
            o.w = sigmoidf_(a0q.w + v.w);
            *(float4*)&ab[off] = o;
        } else if (z == 2) {
            float4 v0q = *(const float4*)(v0v + c);
            float4 vr = *(const float4*)&vbuf[off];
            float4 vf = *(const float4*)&v_first[off];
            float4 o;
            o.x = vr.x + (vf.x - vr.x) * sigmoidf_(v0q.x + v.x);
            o.y = vr.y + (vf.y - vr.y) * sigmoidf_(v0q.y + v.y);
            o.z = vr.z + (vf.z - vr.z) * sigmoidf_(v0q.z + v.z);
            o.w = vr.w + (vf.w - vr.w) * sigmoidf_(v0q.w + v.w);
            *(float4*)&vbuf[off] = o;
        } else {
            *(float4*)&gb[off] = v;
        }
    }
}

// ---------------------------------------------------------------------------
// wkvA (unchanged from round 20 — passed): reg-column Tinv.
// ---------------------------------------------------------------------------
template<int CBT>
__global__ __launch_bounds__(256, 3) void wkvA(
    const float* __restrict__ kb, const float* __restrict__ ab,
    const float* __restrict__ vb, const float* __restrict__ decb,
    const float* __restrict__ k_k, const float* __restrict__ k_a,
    float* __restrict__ Gb, float* __restrict__ Ub,
    float* __restrict__ Bpb, float* __restrict__ Kpb,
    float* __restrict__ wcb, int cb)
{
    __shared__ __align__(16) float sA[64 * STR];   // ApT -> Yk -> Tinv
    __shared__ __align__(16) float sO[64 * STR];   // BpT -> KpT -> YkV
    __shared__ __align__(16) float sT[64 * STR];   // X
    __shared__ float sSeg[4][64];
    const int inst = blockIdx.x;
    const int bhd = inst / CBT, lc = inst % CBT;
    const int dir = bhd & 1, bh = bhd >> 1, b = bh >> 4, h = bh & 15;
    const int c64 = (cb * CBT + lc) * LCH;
    const int tid = threadIdx.x;
    const int lane = tid & 63, seg = tid >> 6;
    const int ch = h * 64 + lane;
    const size_t gbase = (size_t)inst * 4096;

    float loc[16];
    {
        float run = 1.f;
        #pragma unroll
        for (int i = 0; i < 16; i++) {
            int p = seg * 16 + i;
            int t = dir ? (TMAX - (c64 + p)) : (c64 + p);
            float d = decb[((size_t)(b * TT + t)) * CC + ch];
            run *= d; loc[i] = run;
        }
        sSeg[seg][lane] = run;
    }
    __syncthreads();
    float pre = 1.f;
    for (int s2 = 0; s2 < seg; ++s2) pre *= sSeg[s2][lane];
    float kreg[16];
    {
        const float kkl = k_k[ch], kal = k_a[ch];
        #pragma unroll
        for (int i = 0; i < 16; i++) {
            int p = seg * 16 + i;
            int t = dir ? (TMAX - (c64 + p)) : (c64 + p);
            size_t ra = ((size_t)(b * TT + t)) * CC + ch;
            float kraw = kb[ra], asig = ab[ra];
            float kkv = kraw * kkl;
            float s2 = waveReduceSum(kkv * kkv);
            float kkn = kkv / fmaxf(sqrtf(s2), 1e-12f);
            float wc = loc[i] * pre;
            float wx = (i == 0) ? pre : loc[i - 1] * pre;
            float apv = -kkn * wx;
            float bpv = kkn * asig / wc;
            float kpv = kraw * (1.f + (asig - 1.f) * kal) / wc;
            sA[lane * STR + p] = apv;
            sO[lane * STR + p] = bpv;
            kreg[i] = kpv;
            Gb[gbase + p * 64 + lane] = apv;      // Ap spill (row-major [p][ch])
            Bpb[gbase + p * 64 + lane] = bpv;
            Kpb[gbase + p * 64 + lane] = kpv;
            wcb[gbase + p * 64 + lane] = wc;
        }
    }
    __syncthreads();

    const int tr = (tid >> 4) * 4, tc = (tid & 15) * 4;
    // X = tril(Ap @ Bp^T, -1) -> sT
    {
        float acc[4][4] = {};
        gemm64<1, STR, 1, STR>(sA, sO, acc, tr, tc);
        #pragma unroll
        for (int r = 0; r < 4; r++)
            #pragma unroll
            for (int cq = 0; cq < 4; cq++)
                sT[(tr + r) * STR + tc + cq] = (tc + cq < tr + r) ? acc[r][cq] : 0.f;
    }
    __syncthreads();
    // sO <- KpT (from registers)
    #pragma unroll
    for (int i = 0; i < 16; i++)
        sO[lane * STR + seg * 16 + i] = kreg[i];
    __syncthreads();
    // Yk = tril(Ap @ Kp^T, -1) -> regs -> sA
    {
        float acc[4][4] = {};
        gemm64<1, STR, 1, STR>(sA, sO, acc, tr, tc);
        __syncthreads();
        #pragma unroll
        for (int r = 0; r < 4; r++)
            #pragma unroll
            for (int cq = 0; cq < 4; cq++)
                sA[(tr + r) * STR + tc + cq] = (tc + cq < tr + r) ? acc[r][cq] : 0.f;
    }
    __syncthreads();
    // YkV = Yk(sA) @ V(global) -> sO
    {
        float accY[4][4] = {};
        const float* vbase = vb + ((size_t)(b * TT + (dir ? (TMAX - c64) : c64))) * CC
                           + h * 64 + tc;
        const ptrdiff_t vstep = dir ? -(ptrdiff_t)CC : (ptrdiff_t)CC;
        #pragma unroll 2
        for (int j4 = 0; j4 < 64; j4 += 4) {
            float a_[4][4];
            #pragma unroll
            for (int r = 0; r < 4; r++) {
                float4 t4 = *(const float4*)&sA[(tr + r) * STR + j4];
                a_[r][0] = t4.x; a_[r][1] = t4.y; a_[r][2] = t4.z; a_[r][3] = t4.w;
            }
            float4 vq[4];
            #pragma unroll
            for (int kk = 0; kk < 4; kk++)
                vq[kk] = *(const float4*)(vbase + (ptrdiff_t)(j4 + kk) * vstep);
            #pragma unroll
            for (int r = 0; r < 4; r++) {
                accY[r][0] = fmaf(a_[r][0], vq[0].x, fmaf(a_[r][1], vq[1].x,
                             fmaf(a_[r][2], vq[2].x, fmaf(a_[r][3], vq[3].x, accY[r][0]))));
                accY[r][1] = fmaf(a_[r][0], vq[0].y, fmaf(a_[r][1], vq[1].y,
                             fmaf(a_[r][2], vq[2].y, fmaf(a_[r][3], vq[3].y, accY[r][1]))));
                accY[r][2] = fmaf(a_[r][0], vq[0].z, fmaf(a_[r][1], vq[1].z,
                             fmaf(a_[r][2], vq[2].z, fmaf(a_[r][3], vq[3].z, accY[r][2]))));
                accY[r][3] = fmaf(a_[r][0], vq[0].w, fmaf(a_[r][1], vq[1].w,
                             fmaf(a_[r][2], vq[2].w, fmaf(a_[r][3], vq[3].w, accY[r][3]))));
            }
        }
        __syncthreads();
        #pragma unroll
        for (int r = 0; r < 4; r++)
            #pragma unroll
            for (int cq = 0; cq < 4; cq++)
                sO[(tr + r) * STR + tc + cq] = accY[r][cq];
    }
    __syncthreads();
    // Tinv = (I - X)^{-1} -> sA. Column kept in registers; only the broadcast
    // sT row is read from LDS. 2-accumulator ILP halves the dependent chain.
    if (tid < 64) {
        float y[64];
        #pragma unroll
        for (int r = 0; r < 64; ++r) {
            float a0 = 0.f, a1 = 0.f;
            #pragma unroll
            for (int s = 0; s + 1 < r; s += 2) {
                a0 = fmaf(sT[r * STR + s],     y[s],     a0);
                a1 = fmaf(sT[r * STR + s + 1], y[s + 1], a1);
            }
            if (r & 1)
                a0 = fmaf(sT[r * STR + (r - 1)], y[r - 1], a0);
            y[r] = (r == tid) ? 1.f : (a0 + a1);
        }
        #pragma unroll
        for (int r = 0; r < 64; ++r)
            sA[r * STR + tid] = y[r];
    }
    __syncthreads();
    // U0 = Tinv @ YkV ; G = Tinv @ Ap(Gb)
    {
        float accU[4][4] = {};
        gemm64<STR, 1, 1, STR>(sA, sO, accU, tr, tc);
        float accG[4][4] = {};
        gemm64<STR, 1, 1, 64>(sA, Gb + gbase, accG, tr, tc);
        __syncthreads();
        #pragma unroll
        for (int r = 0; r < 4; r++) {
            *(float4*)&Gb[gbase + (tr + r) * 64 + tc] =
                make_float4(accG[r][0], accG[r][1], accG[r][2], accG[r][3]);
            *(float4*)&Ub[gbase + (tr + r) * 64 + tc] =
                make_float4(accU[r][0], accU[r][1], accU[r][2], accU[r][3]);
        }
    }
}

// ---------------------------------------------------------------------------
// wkvB v5 (templated): quarter decomposition + async-STAGE register prefetch.
// Next chunk's G/Bp/Kp/V are loaded to registers right after the LDS-write
// barrier; HBM/L2 latency hides under the U and S compute phases.
// ---------------------------------------------------------------------------
template<int CBT>
__global__ __launch_bounds__(256) void wkvB(
    const float* __restrict__ vb,
    const float* __restrict__ Gb, float* __restrict__ Ub,
    const float* __restrict__ Bpb, const float* __restrict__ Kpb,
    const float* __restrict__ wcb, float* __restrict__ S0b,
    float* __restrict__ Scur, int cb)
{
    __shared__ __align__(16) float sG[64 * STR];    // G[s][j]
    __shared__ __align__(16) float sB[64 * STR];    // Bp[s][j]
    __shared__ __align__(16) float sK[64 * STR];    // Kp[s][j]
    __shared__ __align__(16) float sS[16 * STR];    // S rows subset [i'][j]
    __shared__ __align__(16) float sU[64 * STR3];   // U[s][i']
    __shared__ __align__(16) float sV[64 * STR3];   // V[s][i']
    const int blk = blockIdx.x;
    const int bhd = blk >> 2, q = blk & 3;
    const int dir = bhd & 1, bh = bhd >> 1, b = bh >> 4, h = bh & 15;
    const int tid = threadIdx.x;
    const int i0 = q * 16;

    for (int i = tid; i < 1024; i += 256) {
        int rr = i >> 6, jj = i & 63;
        sS[rr * STR + jj] = Scur[(size_t)bhd * 4096 + (size_t)(i0 + rr) * 64 + jj];
    }

    float4 gR[4], bR[4], kR[4], vR;
    auto preload = [&](int lc) {
        const size_t gbase = (size_t)(bhd * CBT + lc) * 4096;
        #pragma unroll
        for (int j = 0; j < 4; j++) {
            int f4 = tid + 256 * j;
            gR[j] = *(const float4*)&Gb[gbase + (size_t)f4 * 4];
            bR[j] = *(const float4*)&Bpb[gbase + (size_t)f4 * 4];
            kR[j] = *(const float4*)&Kpb[gbase + (size_t)f4 * 4];
        }
        int c64 = (cb * CBT + lc) * LCH;
        int s = tid >> 2, ii = (tid & 3) * 4;
        int t = dir ? (TMAX - (c64 + s)) : (c64 + s);
        vR = *(const float4*)&vb[((size_t)(b * TT + t)) * CC + h * 64 + i0 + ii];
    };
    preload(0);
    __syncthreads();

    for (int lc = 0; lc < CBT; ++lc) {
        const int inst = bhd * CBT + lc;
        const size_t gbase = (size_t)inst * 4096;
        // write prefetched regs -> LDS; snapshot S0b from sS
        #pragma unroll
        for (int j = 0; j < 4; j++) {
            int e = (tid + 256 * j) * 4;
            int rr = e >> 6, jj = e & 63;
            *(float4*)&sG[rr * STR + jj] = gR[j];
            *(float4*)&sB[rr * STR + jj] = bR[j];
            *(float4*)&sK[rr * STR + jj] = kR[j];
        }
        {
            int s = tid >> 2, ii = (tid & 3) * 4;
            *(float4*)&sV[s * STR3 + ii] = vR;
        }
        for (int i = tid; i < 1024; i += 256) {
            int rr = i >> 6, jj = i & 63;
            S0b[gbase + (size_t)(i0 + rr) * 64 + jj] = sS[rr * STR + jj];
        }
        __syncthreads();
        // issue next chunk's loads (latency hides under phases U and S)
        if (lc + 1 < CBT) preload(lc + 1);
        // U[s][i'] = U0[s][i0+i'] + sum_j G[s][j] * S[i'][j]   (64x16, tile 4x1)
        {
            const int ts = (tid >> 4) * 4;
            const int ti = tid & 15;
            float acc[4];
            #pragma unroll
            for (int r = 0; r < 4; r++)
                acc[r] = Ub[gbase + (size_t)(ts + r) * 64 + i0 + ti];
            #pragma unroll 2
            for (int j4 = 0; j4 < 64; j4 += 4) {
                float4 g0 = *(const float4*)&sG[(ts + 0) * STR + j4];
                float4 g1 = *(const float4*)&sG[(ts + 1) * STR + j4];
                float4 g2 = *(const float4*)&sG[(ts + 2) * STR + j4];
                float4 g3 = *(const float4*)&sG[(ts + 3) * STR + j4];
                float4 sv = *(const float4*)&sS[ti * STR + j4];
                acc[0] = fmaf(g0.x,sv.x,fmaf(g0.y,sv.y,fmaf(g0.z,sv.z,fmaf(g0.w,sv.w,acc[0]))));
                acc[1] = fmaf(g1.x,sv.x,fmaf(g1.y,sv.y,fmaf(g1.z,sv.z,fmaf(g1.w,sv.w,acc[1]))));
                acc[2] = fmaf(g2.x,sv.x,fmaf(g2.y,sv.y,fmaf(g2.z,sv.z,fmaf(g2.w,sv.w,acc[2]))));
                acc[3] = fmaf(g3.x,sv.x,fmaf(g3.y,sv.y,fmaf(g3.z,sv.z,fmaf(g3.w,sv.w,acc[3]))));
            }
            #pragma unroll
            for (int r = 0; r < 4; r++) {
                sU[(ts + r) * STR3 + ti] = acc[r];
                Ub[gbase + (size_t)(ts + r) * 64 + i0 + ti] = acc[r];
            }
        }
        __syncthreads();
        // S'[i'][j] = (S + sum_s U[s][i']*Bp[s][j] + sum_s V[s][i']*Kp[s][j]) * w63[j]
        {
            const int ti = tid >> 4;             // 0..15 state row
            const int tj = (tid & 15) * 4;       // 64 cols
            float acc[4] = {};
            for (int s = 0; s < 64; ++s) {
                float u0 = sU[s * STR3 + ti];
                float v0 = sV[s * STR3 + ti];
                float4 bq = *(const float4*)&sB[s * STR + tj];
                float4 kq = *(const float4*)&sK[s * STR + tj];
                acc[0] = fmaf(u0, bq.x, fmaf(v0, kq.x, acc[0]));
                acc[1] = fmaf(u0, bq.y, fmaf(v0, kq.y, acc[1]));
                acc[2] = fmaf(u0, bq.z, fmaf(v0, kq.z, acc[2]));
                acc[3] = fmaf(u0, bq.w, fmaf(v0, kq.w, acc[3]));
            }
            float w63[4];
            #pragma unroll
            for (int cq = 0; cq < 4; cq++)
                w63[cq] = wcb[gbase + 63 * 64 + tj + cq];
            #pragma unroll
            for (int cq = 0; cq < 4; cq++) {
                float sv = sS[ti * STR + tj + cq];
                sS[ti * STR + tj + cq] = (sv + acc[cq]) * w63[cq];
            }
        }
        __syncthreads();
    }
    for (int i = tid; i < 1024; i += 256)
        Scur[(size_t)bhd * 4096 + (size_t)(i0 + (i >> 6)) * 64 + (i & 63)]
            = sS[(i >> 6) * STR + (i & 63)];
}

// ---------------------------------------------------------------------------
// wkvC (templated): + __launch_bounds__(256,3) — LDS 52 KB permits 3/CU,
// declare the occupancy so the allocator caps VGPRs accordingly.
// ---------------------------------------------------------------------------
template<int CBT>
__global__ __launch_bounds__(256, 3) void wkvC(
    const float* __restrict__ rb, const float* __restrict__ vb,
    const float* __restrict__ Bpb, const float* __restrict__ Kpb,
    const float* __restrict__ Ub, const float* __restrict__ S0b,
    const float* __restrict__ wcb, const float* __restrict__ alpha_p,
    float* __restrict__ yb, int cb)
{
    __shared__ __align__(16) float sR[64 * STR];
    __shared__ __align__(16) float sO[64 * STR];
    __shared__ __align__(16) float sT2[64 * STR];
    const int inst = blockIdx.x;
    const int bhd = inst / CBT, lc = inst % CBT;
    const int dir = bhd & 1, bh = bhd >> 1, b = bh >> 4, h = bh & 15;
    const int c64 = (cb * CBT + lc) * LCH;
    const int tid = threadIdx.x, lane = tid & 63, seg = tid >> 6;
    const size_t gbase = (size_t)inst * 4096;
    const float alpha = alpha_p[0];
    const float wscale = dir ? (1.f - alpha) : alpha;
    const bool first = (cb < (32 / CBT));

    #pragma unroll
    for (int i = 0; i < 16; i++) {
        int p = seg * 16 + i;
        int t = dir ? (TMAX - (c64 + p)) : (c64 + p);
        size_t ra = ((size_t)(b * TT + t)) * CC + h * 64 + lane;
        float wc = wcb[gbase + p * 64 + lane];
        sR[lane * STR + p] = rb[ra] * wc;
        sO[lane * STR + p] = Bpb[gbase + p * 64 + lane];
    }
    __syncthreads();
    const int tr = (tid >> 4) * 4, tc = (tid & 15) * 4;
    float accO[4][4] = {};
    {
        float acc[4][4] = {};
        gemm64<1, STR, 1, STR>(sR, sO, acc, tr, tc);
        #pragma unroll
        for (int r = 0; r < 4; r++)
            #pragma unroll
            for (int cq = 0; cq < 4; cq++)
                sT2[(tr + r) * STR + tc + cq] = (tc + cq <= tr + r) ? acc[r][cq] : 0.f;
    }
    __syncthreads();
    for (int i = tid; i < 4096; i += 256)
        sO[(i >> 6) * STR + (i & 63)] = Ub[gbase + i];
    __syncthreads();
    gemm64<STR, 1, 1, STR>(sT2, sO, accO, tr, tc);
    __syncthreads();
    #pragma unroll
    for (int i = 0; i < 16; i++) {
        int p = seg * 16 + i;
        sO[lane * STR + p] = Kpb[gbase + p * 64 + lane];
    }
    __syncthreads();
    {
        float acc[4][4] = {};
        gemm64<1, STR, 1, STR>(sR, sO, acc, tr, tc);
        #pragma unroll
        for (int r = 0; r < 4; r++)
            #pragma unroll
            for (int cq = 0; cq < 4; cq++)
                sT2[(tr + r) * STR + tc + cq] = (tc + cq <= tr + r) ? acc[r][cq] : 0.f;
    }
    __syncthreads();
    #pragma unroll
    for (int i = 0; i < 16; i++) {
        int p = seg * 16 + i;
        int t = dir ? (TMAX - (c64 + p)) : (c64 + p);
        sO[p * STR + lane] = vb[((size_t)(b * TT + t)) * CC + h * 64 + lane];
    }
    __syncthreads();
    gemm64<STR, 1, 1, STR>(sT2, sO, accO, tr, tc);
    __syncthreads();
    for (int i = tid; i < 4096; i += 256)
        sO[(i >> 6) * STR + (i & 63)] = S0b[gbase + i];
    __syncthreads();
    gemm64<1, STR, STR, 1>(sR, sO, accO, tr, tc);
    #pragma unroll
    for (int r = 0; r < 4; r++) {
        int p = tr + r;
        int t = dir ? (TMAX - (c64 + p)) : (c64 + p);
        float* yp = &yb[((size_t)(b * TT + t)) * CC + h * 64 + tc];
        float4 o;
        if (first) {
            o.x = wscale * accO[r][0];
            o.y = wscale * accO[r][1];
            o.z = wscale * accO[r][2];
            o.w = wscale * accO[r][3];
        } else {
            float4 old = *(float4*)yp;
            o.x = old.x + wscale * accO[r][0];
            o.y = old.y + wscale * accO[r][1];
            o.z = old.z + wscale * accO[r][2];
            o.w = old.w + wscale * accO[r][3];
        }
        *(float4*)yp = o;
    }
}

// ---------------------------------------------------------------------------
// Post: GroupNorm + affine + bonus + gating; emits z as split bf16 (hi+lo).
// ---------------------------------------------------------------------------
__global__ __launch_bounds__(256) void post_kernel(
    const float* __restrict__ yb, const float* __restrict__ rbv,
    const float* __restrict__ kbv, const float* __restrict__ abv,
    const float* __restrict__ vbv, const float* __restrict__ gbv,
    const float* __restrict__ kaw, const float* __restrict__ r_k,
    const float* __restrict__ ln_w, const float* __restrict__ ln_b,
    unsigned short* __restrict__ zh, unsigned short* __restrict__ zl)
{
    const int t = blockIdx.x;
    const int tid = threadIdx.x;
    const size_t base = (size_t)t * CC;
    #pragma unroll
    for (int j = 0; j < 4; j++) {
        int c = tid + 256 * j;
        float y = yb[base + c];
        float s1 = waveReduceSum(y);
        float s2 = waveReduceSum(y * y);
        float mu = s1 * (1.0f / 64.0f);
        float var = s2 * (1.0f / 64.0f) - mu * mu;
        float yn = (y - mu) * rsqrtf(var + EPS_GN);
        yn = yn * ln_w[c] + ln_b[c];
        float rv = rbv[base + c];
        float kf = kbv[base + c] * (1.0f + (abv[base + c] - 1.0f) * kaw[c]);
        float vv = vbv[base + c];
        float dot = waveReduceSum(rv * kf * r_k[c]);
        yn += dot * vv;
        float z = yn * gbv[base + c];
        unsigned short h = f2bf(z);
        zh[base + c] = h;
        zl[base + c] = f2bf(z - bf2f(h));
    }
}

// ---------------------------------------------------------------------------
extern "C" void kernel_launch(void* const* d_in, const int* in_sizes, int n_in,
                              void* d_out, int out_size, void* d_ws, size_t ws_size,
                              hipStream_t stream)
{
    (void)in_sizes; (void)n_in; (void)out_size;
    const float* x      = (const float*)d_in[0];
    const float* vfirst = (const float*)d_in[1];
    const float* x_r    = (const float*)d_in[2];
    const float* x_w    = (const float*)d_in[3];
    const float* x_k    = (const float*)d_in[4];
    const float* x_v    = (const float*)d_in[5];
    const float* x_a    = (const float*)d_in[6];
    const float* x_g    = (const float*)d_in[7];
    const float* w0     = (const float*)d_in[8];
    const float* w1     = (const float*)d_in[9];
    const float* w2     = (const float*)d_in[10];
    const float* a0     = (const float*)d_in[11];
    const float* a1     = (const float*)d_in[12];
    const float* a2     = (const float*)d_in[13];
    const float* v0     = (const float*)d_in[14];
    const float* v1     = (const float*)d_in[15];
    const float* v2     = (const float*)d_in[16];
    const float* g1     = (const float*)d_in[17];
    const float* g2     = (const float*)d_in[18];
    const float* k_k    = (const float*)d_in[19];
    const float* k_a    = (const float*)d_in[20];
    const float* r_k    = (const float*)d_in[21];
    const float* Wr     = (const float*)d_in[22];
    const float* Wk     = (const float*)d_in[23];
    const float* Wv     = (const float*)d_in[24];
    const float* Wo     = (const float*)d_in[25];
    const float* ln_w   = (const float*)d_in[26];
    const float* ln_b   = (const float*)d_in[27];
    const float* alpha  = (const float*)d_in[28];

    // big path: CBT=16 chunks/batch needs ~584 MB workspace
    const bool big = (ws_size >= 600ull * 1000 * 1000);
    const int  cbt = big ? 16 : 8;
    const size_t CHB = (size_t)128 * cbt * 4096;

    const size_t SZ = (size_t)BT * CC;
    float* ws   = (float*)d_ws;
    float* rb   = ws + 0 * SZ;
    float* kb   = ws + 1 * SZ;
    float* vb   = ws + 2 * SZ;
    float* decb = ws + 3 * SZ;
    float* ab   = ws + 4 * SZ;
    float* actf = ws + 5 * SZ;
    unsigned short* awh = (unsigned short*)actf;
    unsigned short* awl = awh + (size_t)BT * 64;
    unsigned short* aah = awl + (size_t)BT * 64;
    unsigned short* aal = aah + (size_t)BT * 64;
    unsigned short* avh = aal + (size_t)BT * 64;
    unsigned short* avl = avh + (size_t)BT * 64;
    unsigned short* agh = avl + (size_t)BT * 64;
    unsigned short* agl = agh + (size_t)BT * 192;
    float* Gb   = actf + (size_t)BT * 384;
    float* Ub   = Gb + CHB;
    float* Bpb  = Ub + CHB;
    float* Kpb  = Bpb + CHB;
    float* S0b  = Kpb + CHB;
    float* wcb  = S0b + CHB;
    float* Scur = wcb + CHB;
    unsigned short* W4h = (unsigned short*)(Scur + (size_t)128 * 4096);
    unsigned short* W4l = W4h + (size_t)CC * CC * 4;
    unsigned short* w2th = W4l + (size_t)CC * CC * 4;
    unsigned short* w2tl = w2th + (size_t)CC * 64;
    unsigned short* a2th = w2tl + (size_t)CC * 64;
    unsigned short* a2tl = a2th + (size_t)CC * 64;
    unsigned short* v2th = a2tl + (size_t)CC * 64;
    unsigned short* v2tl = v2th + (size_t)CC * 64;
    unsigned short* g2th = v2tl + (size_t)CC * 64;
    unsigned short* g2tl = g2th + (size_t)CC * 192;
    // stage-1 weight splits (transposed, Npad rows x 1024)
    unsigned short* w1th = g2tl + (size_t)CC * 192;
    unsigned short* w1tl = w1th + (size_t)64 * CC;
    unsigned short* a1th = w1tl + (size_t)64 * CC;
    unsigned short* a1tl = a1th + (size_t)64 * CC;
    unsigned short* v1th = a1tl + (size_t)64 * CC;
    unsigned short* v1tl = v1th + (size_t)64 * CC;
    unsigned short* g1th = v1tl + (size_t)64 * CC;
    unsigned short* g1tl = g1th + (size_t)192 * CC;
    float* outp = (float*)d_out;
    unsigned short* xrh = (unsigned short*)outp;          // [0, SZ) ushorts
    unsigned short* xrl = xrh + SZ;
    unsigned short* xkh = xrl + SZ;
    unsigned short* xkl = xkh + SZ;
    unsigned short* xvh = (unsigned short*)decb;
    unsigned short* xvl = xvh + SZ;
    unsigned short* xwh = (unsigned short*)rb;            // dead until proj gemm
    unsigned short* xwl = xwh + SZ;
    unsigned short* xah = (unsigned short*)kb;
    unsigned short* xal = xah + SZ;
    unsigned short* xgh = (unsigned short*)vb;
    unsigned short* xgl = xgh + SZ;
    float* gb   = outp;
    float* yb   = outp + SZ;
    unsigned short* zAh = (unsigned short*)decb;
    unsigned short* zAl = zAh + SZ;

    dim3 blk(256);
    const int NG_A = BT * (CC / 8);
    dim3 gridA(NG_A / 256);

    // fused x-mix split (all 6 mixes) — reads x once
    conv_split_x6<<<gridA, blk, 0, stream>>>(x, x_r, x_k, x_v, x_w, x_a, x_g,
        xrh, xrl, xkh, xkl, xvh, xvl, xwh, xwl, xah, xal, xgh, xgl);
    // weight conversions (merged: 1 + 1 + 1 launches)
    conv_w4<<<dim3(512, 4), blk, 0, stream>>>(Wr, Wk, Wv, Wo, W4h, W4l);
    conv_w1y<<<dim3(96, 4), blk, 0, stream>>>(w1, a1, v1, g1,
        w1th, w1tl, a1th, a1tl, v1th, v1tl, g1th, g1tl);
    conv_w2y<<<dim3(96, 4), blk, 0, stream>>>(w2, a2, v2, g2,
        w2th, w2tl, a2th, a2tl, v2th, v2tl, g2th, g2tl);

    // LoRA stage-1 on MFMA (must run BEFORE proj gemm overwrites rb/kb/vb)
    lora1_mfma<<<dim3(BT / 128, 6), blk, 0, stream>>>(
        xwh, xwl, xah, xal, xvh, xvl, xgh, xgl,
        w1th, w1tl, a1th, a1tl, v1th, v1tl, g1th, g1tl,
        awh, awl, aah, aal, avh, avl, agh, agl);

    // r, k, v projections in ONE launch (sel via blockIdx.y; W slots 0..2)
    gemm_split_bf16<<<dim3(1024, 3), blk, 0, stream>>>(
        xrh, xrl, xkh, xkl, xvh, xvl, W4h, W4l, rb, kb, vb, 0);

    // LoRA stage-2 on MFMA (writes decb over xv pair — dead after proj gemm)
    lora2_mfma<<<dim3(BT / 128, CC / 64, 4), blk, 0, stream>>>(
        awh, awl, aah, aal, avh, avl, agh, agl,
        w2th, w2tl, a2th, a2tl, v2th, v2tl, g2th, g2tl,
        w0, a0, v0, vfirst, decb, ab, vb, gb);

    // chunked bidirectional WKV
    hipMemsetAsync(Scur, 0, (size_t)128 * 4096 * sizeof(float), stream);
    if (big) {
        for (int cb = 0; cb < 4; ++cb) {
            wkvA<16><<<dim3(2048), blk, 0, stream>>>(kb, ab, vb, decb, k_k, k_a,
                                                     Gb, Ub, Bpb, Kpb, wcb, cb);
            wkvB<16><<<dim3(512), blk, 0, stream>>>(vb, Gb, Ub, Bpb, Kpb, wcb,
                                                    S0b, Scur, cb);
            wkvC<16><<<dim3(2048), blk, 0, stream>>>(rb, vb, Bpb, Kpb, Ub, S0b,
                                                     wcb, alpha, yb, cb);
        }
    } else {
        for (int cb = 0; cb < 8; ++cb) {
            wkvA<8><<<dim3(1024), blk, 0, stream>>>(kb, ab, vb, decb, k_k, k_a,
                                                    Gb, Ub, Bpb, Kpb, wcb, cb);
            wkvB<8><<<dim3(512), blk, 0, stream>>>(vb, Gb, Ub, Bpb, Kpb, wcb,
                                                   S0b, Scur, cb);
            wkvC<8><<<dim3(1024), blk, 0, stream>>>(rb, vb, Bpb, Kpb, Ub, S0b,
                                                    wcb, alpha, yb, cb);
        }
    }

    // groupnorm + bonus + gate -> split bf16 z (into decb's slot)
    post_kernel<<<dim3(BT), blk, 0, stream>>>(yb, rb, kb, ab, vb, gb, k_a, r_k,
                                              ln_w, ln_b, zAh, zAl);
    // v_first passthrough then final projection (W slot 3 = Wo)
    hipMemcpyAsync(outp + SZ, vfirst, SZ * sizeof(float),
                   hipMemcpyDeviceToDevice, stream);
    gemm_split_bf16<<<dim3(1024, 1), blk, 0, stream>>>(
        zAh, zAl, zAh, zAl, zAh, zAl, W4h, W4l, outp, outp, outp, 3);
}

// Round 22
// 2661.690 us; speedup vs baseline: 1.1235x; 1.1235x over previous
//
#include <hip/hip_runtime.h>
#include <hip/hip_bf16.h>
#include <math.h>

#define BB 4
#define TT 4096
#define CC 1024
#define HH 16
#define NN 64
#define BT (BB*TT)            // 16384 rows
#define EPS_GN 6.4e-4f        // 1e-5 * 8^2
#define TMAX (TT-1)
#define LCH 64                // chunk length
#define STR 68                // padded LDS row stride (multiple of 4 -> b128)
#define STR3 20               // quarter-width padded stride (16+4)

typedef __attribute__((ext_vector_type(8))) short bf16x8;
typedef __attribute__((ext_vector_type(4))) float f32x4;

__device__ __forceinline__ float sigmoidf_(float x) {
    return 1.0f / (1.0f + expf(-x));
}

__device__ __forceinline__ float waveReduceSum(float v) {
    #pragma unroll
    for (int off = 32; off > 0; off >>= 1)
        v += __shfl_xor(v, off, 64);
    return v;
}

__device__ __forceinline__ unsigned short f2bf(float f) {
    unsigned u = __float_as_uint(f);
    u += 0x7FFFu + ((u >> 16) & 1u);
    return (unsigned short)(u >> 16);
}
__device__ __forceinline__ float bf2f(unsigned short h) {
    return __uint_as_float(((unsigned)h) << 16);
}

__device__ __forceinline__ void gll16(const unsigned short* g, unsigned short* l) {
    __builtin_amdgcn_global_load_lds(
        (__attribute__((address_space(1))) void*)(g),
        (__attribute__((address_space(3))) void*)(l), 16, 0, 0);
}

// acc[r][c] += sum_k A(tr+r,k)*B(tc+c,k); element A(i,k)=A[i*SA0+k*SA1].
template<int SA0,int SA1,int SB0,int SB1>
__device__ __forceinline__ void gemm64(const float* __restrict__ A,
                                       const float* __restrict__ B,
                                       float acc[4][4], int tr, int tc) {
    #pragma unroll 2
    for (int kx = 0; kx < 64; kx += 4) {
        float a_[4][4];   // [r][kk]
        if (SA0 == 1) {
            #pragma unroll
            for (int kk = 0; kk < 4; kk++) {
                float4 t = *(const float4*)&A[tr + (kx + kk) * SA1];
                a_[0][kk] = t.x; a_[1][kk] = t.y; a_[2][kk] = t.z; a_[3][kk] = t.w;
            }
        } else {
            #pragma unroll
            for (int r = 0; r < 4; r++) {
                float4 t = *(const float4*)&A[(tr + r) * SA0 + kx];
                a_[r][0] = t.x; a_[r][1] = t.y; a_[r][2] = t.z; a_[r][3] = t.w;
            }
        }
        float b_[4][4];   // [cq][kk]
        if (SB0 == 1) {
            #pragma unroll
            for (int kk = 0; kk < 4; kk++) {
                float4 t = *(const float4*)&B[tc + (kx + kk) * SB1];
                b_[0][kk] = t.x; b_[1][kk] = t.y; b_[2][kk] = t.z; b_[3][kk] = t.w;
            }
        } else {
            #pragma unroll
            for (int cq = 0; cq < 4; cq++) {
                float4 t = *(const float4*)&B[(tc + cq) * SB0 + kx];
                b_[cq][0] = t.x; b_[cq][1] = t.y; b_[cq][2] = t.z; b_[cq][3] = t.w;
            }
        }
        #pragma unroll
        for (int r = 0; r < 4; r++)
            #pragma unroll
            for (int cq = 0; cq < 4; cq++)
                #pragma unroll
                for (int kk = 0; kk < 4; kk++)
                    acc[r][cq] = fmaf(a_[r][kk], b_[cq][kk], acc[r][cq]);
    }
}

// ---------------------------------------------------------------------------
// Fused mix+split for ALL SIX mixes: reads x (+prev) ONCE, emits 6 hi/lo pairs.
// ---------------------------------------------------------------------------
__global__ __launch_bounds__(256) void conv_split_x6(
    const float* __restrict__ X,
    const float* __restrict__ mr, const float* __restrict__ mk,
    const float* __restrict__ mv, const float* __restrict__ mw,
    const float* __restrict__ ma, const float* __restrict__ mg,
    unsigned short* __restrict__ rH, unsigned short* __restrict__ rL,
    unsigned short* __restrict__ kH, unsigned short* __restrict__ kL,
    unsigned short* __restrict__ vH, unsigned short* __restrict__ vL,
    unsigned short* __restrict__ wH, unsigned short* __restrict__ wL,
    unsigned short* __restrict__ aH, unsigned short* __restrict__ aL,
    unsigned short* __restrict__ gH, unsigned short* __restrict__ gL)
{
    int g = blockIdx.x * 256 + threadIdx.x;
    int m = g >> 7;
    int k = (g & 127) * 8;
    const float* px = X + (size_t)m * CC + k;
    float xv8[8], pv[8];
    {
        float4 x0 = *(const float4*)px;
        float4 x1 = *(const float4*)(px + 4);
        xv8[0]=x0.x; xv8[1]=x0.y; xv8[2]=x0.z; xv8[3]=x0.w;
        xv8[4]=x1.x; xv8[5]=x1.y; xv8[6]=x1.z; xv8[7]=x1.w;
    }
    if ((m & (TT - 1)) == 0) {
        #pragma unroll
        for (int j = 0; j < 8; j++) pv[j] = 0.f;
    } else {
        float4 p0 = *(const float4*)(px - CC);
        float4 p1 = *(const float4*)(px - CC + 4);
        pv[0]=p0.x; pv[1]=p0.y; pv[2]=p0.z; pv[3]=p0.w;
        pv[4]=p1.x; pv[5]=p1.y; pv[6]=p1.z; pv[7]=p1.w;
    }
    const float* mixes[6] = {mr, mk, mv, mw, ma, mg};
    unsigned short* His[6] = {rH, kH, vH, wH, aH, gH};
    unsigned short* Los[6] = {rL, kL, vL, wL, aL, gL};
    for (int s = 0; s < 6; s++) {
        float4 m0 = *(const float4*)(mixes[s] + k);
        float4 m1 = *(const float4*)(mixes[s] + k + 4);
        float mv8[8] = {m0.x,m0.y,m0.z,m0.w,m1.x,m1.y,m1.z,m1.w};
        unsigned short hi[8], lo[8];
        #pragma unroll
        for (int j = 0; j < 8; j++) {
            float a = xv8[j] + (pv[j] - xv8[j]) * mv8[j];
            hi[j] = f2bf(a);
            lo[j] = f2bf(a - bf2f(hi[j]));
        }
        uint4 H, L;
        H.x = (unsigned)hi[0] | ((unsigned)hi[1] << 16);
        H.y = (unsigned)hi[2] | ((unsigned)hi[3] << 16);
        H.z = (unsigned)hi[4] | ((unsigned)hi[5] << 16);
        H.w = (unsigned)hi[6] | ((unsigned)hi[7] << 16);
        L.x = (unsigned)lo[0] | ((unsigned)lo[1] << 16);
        L.y = (unsigned)lo[2] | ((unsigned)lo[3] << 16);
        L.z = (unsigned)lo[4] | ((unsigned)lo[5] << 16);
        L.w = (unsigned)lo[6] | ((unsigned)lo[7] << 16);
        *(uint4*)(His[s] + (size_t)g * 8) = H;
        *(uint4*)(Los[s] + (size_t)g * 8) = L;
    }
}

// ---------------------------------------------------------------------------
// All 4 big weights -> 4-slot split-bf16 buffer. blockIdx.y selects W & slot.
// ---------------------------------------------------------------------------
__global__ __launch_bounds__(256) void conv_w4(
    const float* __restrict__ Wr, const float* __restrict__ Wk,
    const float* __restrict__ Wv, const float* __restrict__ Wo,
    unsigned short* __restrict__ Hi, unsigned short* __restrict__ Lo)
{
    int g = blockIdx.x * 256 + threadIdx.x;      // 0 .. CC*CC/8-1
    int y = blockIdx.y;
    const float* W = (y == 0) ? Wr : (y == 1) ? Wk : (y == 2) ? Wv : Wo;
    size_t doff = (size_t)y * CC * CC;
    int m = g >> 7;
    int k = (g & 127) * 8;
    const float* px = W + (size_t)m * CC + k;
    float a[8];
    {
        float4 x0 = *(const float4*)px;
        float4 x1 = *(const float4*)(px + 4);
        a[0]=x0.x; a[1]=x0.y; a[2]=x0.z; a[3]=x0.w;
        a[4]=x1.x; a[5]=x1.y; a[6]=x1.z; a[7]=x1.w;
    }
    unsigned short hi[8], lo[8];
    #pragma unroll
    for (int j = 0; j < 8; j++) {
        hi[j] = f2bf(a[j]);
        lo[j] = f2bf(a[j] - bf2f(hi[j]));
    }
    uint4 H, L;
    H.x = (unsigned)hi[0] | ((unsigned)hi[1] << 16);
    H.y = (unsigned)hi[2] | ((unsigned)hi[3] << 16);
    H.z = (unsigned)hi[4] | ((unsigned)hi[5] << 16);
    H.w = (unsigned)hi[6] | ((unsigned)hi[7] << 16);
    L.x = (unsigned)lo[0] | ((unsigned)lo[1] << 16);
    L.y = (unsigned)lo[2] | ((unsigned)lo[3] << 16);
    L.z = (unsigned)lo[4] | ((unsigned)lo[5] << 16);
    L.w = (unsigned)lo[6] | ((unsigned)lo[7] << 16);
    *(uint4*)(Hi + doff + (size_t)g * 8) = H;
    *(uint4*)(Lo + doff + (size_t)g * 8) = L;
}

// ---------------------------------------------------------------------------
// Stage-1 weight transpose+split, 4 slices in one launch (blockIdx.y):
// W (1024, N) n-contig -> (Npad, 1024) k-contig hi/lo, rows >= N zero.
// ---------------------------------------------------------------------------
__global__ __launch_bounds__(256) void conv_w1y(
    const float* __restrict__ w1, const float* __restrict__ a1,
    const float* __restrict__ v1, const float* __restrict__ g1,
    unsigned short* __restrict__ w1th, unsigned short* __restrict__ w1tl,
    unsigned short* __restrict__ a1th, unsigned short* __restrict__ a1tl,
    unsigned short* __restrict__ v1th, unsigned short* __restrict__ v1tl,
    unsigned short* __restrict__ g1th, unsigned short* __restrict__ g1tl)
{
    const int y = blockIdx.y;
    const float* W = (y == 0) ? w1 : (y == 1) ? a1 : (y == 2) ? v1 : g1;
    unsigned short* Hi = (y == 0) ? w1th : (y == 1) ? a1th : (y == 2) ? v1th : g1th;
    unsigned short* Lo = (y == 0) ? w1tl : (y == 1) ? a1tl : (y == 2) ? v1tl : g1tl;
    const int N    = (y == 2) ? 32 : (y == 3) ? 160 : 64;
    const int Npad = (y == 3) ? 192 : 64;
    int idx = blockIdx.x * 256 + threadIdx.x;
    if (idx >= Npad * 128) return;
    int n = idx >> 7, k0 = (idx & 127) * 8;
    unsigned short h8[8], l8[8];
    #pragma unroll
    for (int j = 0; j < 8; j++) {
        int k = k0 + j;
        float v = (n < N) ? W[(size_t)k * N + n] : 0.f;
        h8[j] = f2bf(v);
        l8[j] = f2bf(v - bf2f(h8[j]));
    }
    uint4 H, L;
    H.x = (unsigned)h8[0] | ((unsigned)h8[1] << 16);
    H.y = (unsigned)h8[2] | ((unsigned)h8[3] << 16);
    H.z = (unsigned)h8[4] | ((unsigned)h8[5] << 16);
    H.w = (unsigned)h8[6] | ((unsigned)h8[7] << 16);
    L.x = (unsigned)l8[0] | ((unsigned)l8[1] << 16);
    L.y = (unsigned)l8[2] | ((unsigned)l8[3] << 16);
    L.z = (unsigned)l8[4] | ((unsigned)l8[5] << 16);
    L.w = (unsigned)l8[6] | ((unsigned)l8[7] << 16);
    *(uint4*)(Hi + (size_t)n * CC + k0) = H;
    *(uint4*)(Lo + (size_t)n * CC + k0) = L;
}

// ---------------------------------------------------------------------------
// Stage-2 weight transpose+split, 4 slices in one launch (blockIdx.y):
// W (K,CC) n-contig -> (CC,Kp) k-contig hi/lo, cols >= K zero.
// ---------------------------------------------------------------------------
__global__ __launch_bounds__(256) void conv_w2y(
    const float* __restrict__ w2, const float* __restrict__ a2,
    const float* __restrict__ v2, const float* __restrict__ g2,
    unsigned short* __restrict__ w2th, unsigned short* __restrict__ w2tl,
    unsigned short* __restrict__ a2th, unsigned short* __restrict__ a2tl,
    unsigned short* __restrict__ v2th, unsigned short* __restrict__ v2tl,
    unsigned short* __restrict__ g2th, unsigned short* __restrict__ g2tl)
{
    const int y = blockIdx.y;
    const float* W = (y == 0) ? w2 : (y == 1) ? a2 : (y == 2) ? v2 : g2;
    unsigned short* Hi = (y == 0) ? w2th : (y == 1) ? a2th : (y == 2) ? v2th : g2th;
    unsigned short* Lo = (y == 0) ? w2tl : (y == 1) ? a2tl : (y == 2) ? v2tl : g2tl;
    const int K  = (y == 2) ? 32 : (y == 3) ? 160 : 64;
    const int Kp = (y == 3) ? 192 : 64;
    int idx = blockIdx.x * 256 + threadIdx.x;
    int nk8 = Kp >> 3;
    if (idx >= CC * nk8) return;
    int n = idx / nk8, k0 = (idx - n * nk8) * 8;
    unsigned short h8[8], l8[8];
    #pragma unroll
    for (int j = 0; j < 8; j++) {
        int k = k0 + j;
        float v = (k < K) ? W[(size_t)k * CC + n] : 0.f;
        h8[j] = f2bf(v);
        l8[j] = f2bf(v - bf2f(h8[j]));
    }
    uint4 H, L;
    H.x = (unsigned)h8[0] | ((unsigned)h8[1] << 16);
    H.y = (unsigned)h8[2] | ((unsigned)h8[3] << 16);
    H.z = (unsigned)h8[4] | ((unsigned)h8[5] << 16);
    H.w = (unsigned)h8[6] | ((unsigned)h8[7] << 16);
    L.x = (unsigned)l8[0] | ((unsigned)l8[1] << 16);
    L.y = (unsigned)l8[2] | ((unsigned)l8[3] << 16);
    L.z = (unsigned)l8[4] | ((unsigned)l8[5] << 16);
    L.w = (unsigned)l8[6] | ((unsigned)l8[7] << 16);
    *(uint4*)(Hi + (size_t)n * Kp + k0) = H;
    *(uint4*)(Lo + (size_t)n * Kp + k0) = L;
}

// ---------------------------------------------------------------------------
// Split-bf16 MFMA GEMM v3 (unchanged — passed)
// ---------------------------------------------------------------------------
__global__ __launch_bounds__(256, 3) void gemm_split_bf16(
    const unsigned short* __restrict__ A0h, const unsigned short* __restrict__ A0l,
    const unsigned short* __restrict__ A1h, const unsigned short* __restrict__ A1l,
    const unsigned short* __restrict__ A2h, const unsigned short* __restrict__ A2l,
    const unsigned short* __restrict__ W4h, const unsigned short* __restrict__ W4l,
    float* __restrict__ O0, float* __restrict__ O1, float* __restrict__ O2,
    int wbase)
{
    __shared__ __align__(16) unsigned short lds[4][128 * 32];   // 32 KB
    const int sel = blockIdx.y;
    const unsigned short* Ah = (sel == 0) ? A0h : (sel == 1) ? A1h : A2h;
    const unsigned short* Al = (sel == 0) ? A0l : (sel == 1) ? A1l : A2l;
    float* Out = (sel == 0) ? O0 : (sel == 1) ? O1 : O2;
    const unsigned short* Bh = W4h + (size_t)(wbase + sel) * CC * CC;
    const unsigned short* Bl = W4l + (size_t)(wbase + sel) * CC * CC;
    const int tid = threadIdx.x, lane = tid & 63, wave = tid >> 6;
    const int wm = (wave >> 1) * 64, wn = (wave & 1) * 64;
    const int wg = blockIdx.x;
    const int xcd = wg & 7;
    const int j = wg >> 3;
    const int m0 = ((j >> 3) * 8 + xcd) * 128;
    const int n0 = (j & 7) * 128;

    f32x4 acc[4][4];
    #pragma unroll
    for (int i = 0; i < 4; i++)
        #pragma unroll
        for (int jj = 0; jj < 4; jj++)
            acc[i][jj] = (f32x4){0.f, 0.f, 0.f, 0.f};

    for (int k0 = 0; k0 < CC; k0 += 32) {
        #pragma unroll
        for (int p = 0; p < 4; p++) {
            const unsigned short* sbase = (p == 0) ? Ah : (p == 1) ? Al
                                        : (p == 2) ? Bh : Bl;
            const int rbase = (p < 2) ? m0 : n0;
            #pragma unroll
            for (int i = 0; i < 2; i++) {
                int slot = i * 256 + wave * 64 + lane;   // 0..511
                int row = slot >> 2, gsl = slot & 3;
                const unsigned short* src = sbase
                    + (size_t)(rbase + row) * CC + k0 + ((gsl ^ (row & 3)) * 8);
                gll16(src, &lds[p][(size_t)(i * 256 + wave * 64) * 8]);
            }
        }
        __syncthreads();

        const int gk = lane >> 4;
        bf16x8 bhf[4], blf[4];
        #pragma unroll
        for (int nt = 0; nt < 4; nt++) {
            int col = wn + nt * 16 + (lane & 15);
            int el = col * 32 + ((gk ^ (col & 3)) * 8);
            bhf[nt] = *(const bf16x8*)&lds[2][el];
            blf[nt] = *(const bf16x8*)&lds[3][el];
        }
        #pragma unroll
        for (int mt = 0; mt < 4; mt++) {
            int row = wm + mt * 16 + (lane & 15);
            int el = row * 32 + ((gk ^ (row & 3)) * 8);
            bf16x8 ahf = *(const bf16x8*)&lds[0][el];
            bf16x8 alf = *(const bf16x8*)&lds[1][el];
            #pragma unroll
            for (int nt = 0; nt < 4; nt++) {
                acc[mt][nt] = __builtin_amdgcn_mfma_f32_16x16x32_bf16(
                    ahf, bhf[nt], acc[mt][nt], 0, 0, 0);
                acc[mt][nt] = __builtin_amdgcn_mfma_f32_16x16x32_bf16(
                    alf, bhf[nt], acc[mt][nt], 0, 0, 0);
                acc[mt][nt] = __builtin_amdgcn_mfma_f32_16x16x32_bf16(
                    ahf, blf[nt], acc[mt][nt], 0, 0, 0);
            }
        }
        __syncthreads();
    }
    #pragma unroll
    for (int mt = 0; mt < 4; mt++)
        #pragma unroll
        for (int nt = 0; nt < 4; nt++) {
            int col = n0 + wn + nt * 16 + (lane & 15);
            #pragma unroll
            for (int r = 0; r < 4; r++) {
                int row = m0 + wm + mt * 16 + (lane >> 4) * 4 + r;
                Out[(size_t)row * CC + col] = acc[mt][nt][r];
            }
        }
}

// ---------------------------------------------------------------------------
// LoRA stage-1 on MFMA (unchanged — passed)
// ---------------------------------------------------------------------------
__global__ __launch_bounds__(256, 3) void lora1_mfma(
    const unsigned short* __restrict__ xwh, const unsigned short* __restrict__ xwl,
    const unsigned short* __restrict__ xah, const unsigned short* __restrict__ xal,
    const unsigned short* __restrict__ xvh, const unsigned short* __restrict__ xvl,
    const unsigned short* __restrict__ xgh, const unsigned short* __restrict__ xgl,
    const unsigned short* __restrict__ w1th, const unsigned short* __restrict__ w1tl,
    const unsigned short* __restrict__ a1th, const unsigned short* __restrict__ a1tl,
    const unsigned short* __restrict__ v1th, const unsigned short* __restrict__ v1tl,
    const unsigned short* __restrict__ g1th, const unsigned short* __restrict__ g1tl,
    unsigned short* __restrict__ awh, unsigned short* __restrict__ awl,
    unsigned short* __restrict__ aah, unsigned short* __restrict__ aal,
    unsigned short* __restrict__ avh, unsigned short* __restrict__ avl,
    unsigned short* __restrict__ agh, unsigned short* __restrict__ agl)
{
    __shared__ __align__(16) unsigned short lds[12288];   // 24 KB
    const int y = blockIdx.y;
    const unsigned short *Ah, *Al, *Bh, *Bl;
    unsigned short *Oh, *Ol;
    int n0, epi, Kp;
    if (y == 0)      { Ah=xwh; Al=xwl; Bh=w1th; Bl=w1tl; Oh=awh; Ol=awl; n0=0; epi=1; Kp=64; }
    else if (y == 1) { Ah=xah; Al=xal; Bh=a1th; Bl=a1tl; Oh=aah; Ol=aal; n0=0; epi=0; Kp=64; }
    else if (y == 2) { Ah=xvh; Al=xvl; Bh=v1th; Bl=v1tl; Oh=avh; Ol=avl; n0=0; epi=0; Kp=64; }
    else             { Ah=xgh; Al=xgl; Bh=g1th + (size_t)(y-3)*64*CC;
                       Bl=g1tl + (size_t)(y-3)*64*CC; Oh=agh; Ol=agl;
                       n0=(y-3)*64; epi=2; Kp=192; }

    const int tid = threadIdx.x, lane = tid & 63, wave = tid >> 6;
    const int wm = (wave >> 1) * 64, wn = (wave & 1) * 32;
    const int m0 = blockIdx.x * 128;

    f32x4 acc[4][2];
    #pragma unroll
    for (int i = 0; i < 4; i++)
        #pragma unroll
        for (int jj = 0; jj < 2; jj++)
            acc[i][jj] = (f32x4){0.f, 0.f, 0.f, 0.f};

    for (int k0 = 0; k0 < CC; k0 += 32) {
        #pragma unroll
        for (int p = 0; p < 2; p++) {
            const unsigned short* sbase = (p == 0) ? Ah : Al;
            #pragma unroll
            for (int i = 0; i < 2; i++) {
                int slot = i * 256 + wave * 64 + lane;
                int row = slot >> 2, gsl = slot & 3;
                const unsigned short* src = sbase
                    + (size_t)(m0 + row) * CC + k0 + ((gsl ^ (row & 3)) * 8);
                gll16(src, &lds[(size_t)(p * 4096) + (size_t)(i * 256 + wave * 64) * 8]);
            }
        }
        #pragma unroll
        for (int p = 0; p < 2; p++) {
            const unsigned short* sbase = (p == 0) ? Bh : Bl;
            int slot = wave * 64 + lane;
            int row = slot >> 2, gsl = slot & 3;
            const unsigned short* src = sbase
                + (size_t)row * CC + k0 + ((gsl ^ (row & 3)) * 8);
            gll16(src, &lds[(size_t)(8192 + p * 2048) + (size_t)slot * 8]);
        }
        __syncthreads();

        const int gk = lane >> 4;
        bf16x8 bhf[2], blf[2];
        #pragma unroll
        for (int nt = 0; nt < 2; nt++) {
            int col = wn + nt * 16 + (lane & 15);
            int el = col * 32 + ((gk ^ (col & 3)) * 8);
            bhf[nt] = *(const bf16x8*)&lds[8192 + el];
            blf[nt] = *(const bf16x8*)&lds[10240 + el];
        }
        #pragma unroll
        for (int mt = 0; mt < 4; mt++) {
            int row = wm + mt * 16 + (lane & 15);
            int el = row * 32 + ((gk ^ (row & 3)) * 8);
            bf16x8 ahf = *(const bf16x8*)&lds[el];
            bf16x8 alf = *(const bf16x8*)&lds[4096 + el];
            #pragma unroll
            for (int nt = 0; nt < 2; nt++) {
                acc[mt][nt] = __builtin_amdgcn_mfma_f32_16x16x32_bf16(
                    ahf, bhf[nt], acc[mt][nt], 0, 0, 0);
                acc[mt][nt] = __builtin_amdgcn_mfma_f32_16x16x32_bf16(
                    alf, bhf[nt], acc[mt][nt], 0, 0, 0);
                acc[mt][nt] = __builtin_amdgcn_mfma_f32_16x16x32_bf16(
                    ahf, blf[nt], acc[mt][nt], 0, 0, 0);
            }
        }
        __syncthreads();
    }
    #pragma unroll
    for (int mt = 0; mt < 4; mt++)
        #pragma unroll
        for (int nt = 0; nt < 2; nt++) {
            int col = n0 + wn + nt * 16 + (lane & 15);
            #pragma unroll
            for (int r = 0; r < 4; r++) {
                int row = m0 + wm + mt * 16 + (lane >> 4) * 4 + r;
                float v = acc[mt][nt][r];
                if (epi == 1) v = tanhf(v);
                else if (epi == 2) v = sigmoidf_(v);
                unsigned short h = f2bf(v);
                size_t off = (size_t)row * Kp + col;
                Oh[off] = h;
                Ol[off] = f2bf(v - bf2f(h));
            }
        }
}

// ---------------------------------------------------------------------------
// LoRA stage-2 on MFMA (unchanged — passed)
// ---------------------------------------------------------------------------
__global__ __launch_bounds__(256, 3) void lora2_mfma(
    const unsigned short* __restrict__ awh, const unsigned short* __restrict__ awl,
    const unsigned short* __restrict__ aah, const unsigned short* __restrict__ aal,
    const unsigned short* __restrict__ avh, const unsigned short* __restrict__ avl,
    const unsigned short* __restrict__ agh, const unsigned short* __restrict__ agl,
    const unsigned short* __restrict__ w2h, const unsigned short* __restrict__ w2l,
    const unsigned short* __restrict__ a2h, const unsigned short* __restrict__ a2l,
    const unsigned short* __restrict__ v2h, const unsigned short* __restrict__ v2l,
    const unsigned short* __restrict__ g2h, const unsigned short* __restrict__ g2l,
    const float* __restrict__ w0, const float* __restrict__ a0v,
    const float* __restrict__ v0v, const float* __restrict__ v_first,
    float* __restrict__ decb, float* __restrict__ ab,
    float* __restrict__ vbuf, float* __restrict__ gb)
{
    __shared__ __align__(16) unsigned short lds[24576];   // 48 KB
    const int z = blockIdx.z;
    const unsigned short *Ah, *Al, *Bh, *Bl; int Kp;
    if (z == 0)      { Ah = awh; Al = awl; Bh = w2h; Bl = w2l; Kp = 64;  }
    else if (z == 1) { Ah = aah; Al = aal; Bh = a2h; Bl = a2l; Kp = 64;  }
    else if (z == 2) { Ah = avh; Al = avl; Bh = v2h; Bl = v2l; Kp = 64;  }
    else             { Ah = agh; Al = agl; Bh = g2h; Bl = g2l; Kp = 192; }

    const int tid = threadIdx.x, lane = tid & 63, wave = tid >> 6;
    const int wm = (wave >> 1) * 64, wn = (wave & 1) * 32;
    const int m0 = blockIdx.x * 128, n0 = blockIdx.y * 64;

    f32x4 acc[4][2];
    #pragma unroll
    for (int i = 0; i < 4; i++)
        #pragma unroll
        for (int jj = 0; jj < 2; jj++)
            acc[i][jj] = (f32x4){0.f, 0.f, 0.f, 0.f};

    for (int k0 = 0; k0 < Kp; k0 += 64) {
        #pragma unroll
        for (int p = 0; p < 2; p++) {
            const unsigned short* sbase = (p == 0) ? Ah : Al;
            #pragma unroll
            for (int i = 0; i < 4; i++) {
                int slot = i * 256 + wave * 64 + lane;
                int row = slot >> 3, gsl = slot & 7;
                const unsigned short* src = sbase
                    + (size_t)(m0 + row) * Kp + k0 + ((gsl ^ (row & 7)) * 8);
                gll16(src, &lds[(size_t)(p * 8192) + (size_t)(i * 256 + wave * 64) * 8]);
            }
        }
        #pragma unroll
        for (int p = 0; p < 2; p++) {
            const unsigned short* sbase = (p == 0) ? Bh : Bl;
            #pragma unroll
            for (int i = 0; i < 2; i++) {
                int slot = i * 256 + wave * 64 + lane;
                int row = slot >> 3, gsl = slot & 7;
                const unsigned short* src = sbase
                    + (size_t)(n0 + row) * Kp + k0 + ((gsl ^ (row & 7)) * 8);
                gll16(src, &lds[(size_t)(16384 + p * 4096) + (size_t)(i * 256 + wave * 64) * 8]);
            }
        }
        __syncthreads();

        #pragma unroll
        for (int ks = 0; ks < 2; ks++) {
            bf16x8 bhf[2], blf[2];
            #pragma unroll
            for (int nt = 0; nt < 2; nt++) {
                int col = wn + nt * 16 + (lane & 15);
                int gk = ks * 4 + (lane >> 4);
                int el = col * 64 + ((gk ^ (col & 7)) * 8);
                bhf[nt] = *(const bf16x8*)&lds[16384 + el];
                blf[nt] = *(const bf16x8*)&lds[20480 + el];
            }
            #pragma unroll
            for (int mt = 0; mt < 4; mt++) {
                int row = wm + mt * 16 + (lane & 15);
                int gk = ks * 4 + (lane >> 4);
                int el = row * 64 + ((gk ^ (row & 7)) * 8);
                bf16x8 ahf = *(const bf16x8*)&lds[el];
                bf16x8 alf = *(const bf16x8*)&lds[8192 + el];
                #pragma unroll
                for (int nt = 0; nt < 2; nt++) {
                    acc[mt][nt] = __builtin_amdgcn_mfma_f32_16x16x32_bf16(
                        ahf, bhf[nt], acc[mt][nt], 0, 0, 0);
                    acc[mt][nt] = __builtin_amdgcn_mfma_f32_16x16x32_bf16(
                        alf, bhf[nt], acc[mt][nt], 0, 0, 0);
                    acc[mt][nt] = __builtin_amdgcn_mfma_f32_16x16x32_bf16(
                        ahf, blf[nt], acc[mt][nt], 0, 0, 0);
                }
            }
        }
        __syncthreads();
    }
    float* cf = (float*)&lds[0];
    #pragma unroll
    for (int mt = 0; mt < 4; mt++)
        #pragma unroll
        for (int nt = 0; nt < 2; nt++)
            #pragma unroll
            for (int r = 0; r < 4; r++) {
                int row = wm + mt * 16 + (lane >> 4) * 4 + r;
                int col = wn + nt * 16 + (lane & 15);
                cf[row * 68 + col] = acc[mt][nt][r];
            }
    __syncthreads();
    #pragma unroll
    for (int i = 0; i < 8; i++) {
        int idx = tid + 256 * i;
        int row = idx >> 4, c4 = (idx & 15) * 4;
        float4 v = *(float4*)&cf[row * 68 + c4];
        int gm = m0 + row;
        int c = n0 + c4;
        size_t off = (size_t)gm * CC + c;
        if (z == 0) {
            float4 w0q = *(const float4*)(w0 + c);
            float4 o;
            o.x = expf(-expf(-log1pf(expf(-(w0q.x + v.x))) - 0.5f));
            o.y = expf(-expf(-log1pf(expf(-(w0q.y + v.y))) - 0.5f));
            o.z = expf(-expf(-log1pf(expf(-(w0q.z + v.z))) - 0.5f));
            o.w = expf(-expf(-log1pf(expf(-(w0q.w + v.w))) - 0.5f));
            *(float4*)&decb[off] = o;
        } else if (z == 1) {
            float4 a0q = *(const float4*)(a0v + c);
            float4 o;
            o.x = sigmoidf_(a0q.x + v.x);
            o.y = sigmoidf_(a0q.y + v.y);
            o.z = sigmoidf_(a0q.z + v.z);
            o.w = sigmoidf_(a0q.w + v.w);
            *(float4*)&ab[off] = o;
        } else if (z == 2) {
            float4 v0q = *(const float4*)(v0v + c);
            float4 vr = *(const float4*)&vbuf[off];
            float4 vf = *(const float4*)&v_first[off];
            float4 o;
            o.x = vr.x + (vf.x - vr.x) * sigmoidf_(v0q.x + v.x);
            o.y = vr.y + (vf.y - vr.y) * sigmoidf_(v0q.y + v.y);
            o.z = vr.z + (vf.z - vr.z) * sigmoidf_(v0q.z + v.z);
            o.w = vr.w + (vf.w - vr.w) * sigmoidf_(v0q.w + v.w);
            *(float4*)&vbuf[off] = o;
        } else {
            *(float4*)&gb[off] = v;
        }
    }
}

// ---------------------------------------------------------------------------
// wkvA (round-20 form — passed): reg-column Tinv.
// ---------------------------------------------------------------------------
template<int CBT>
__global__ __launch_bounds__(256, 3) void wkvA(
    const float* __restrict__ kb, const float* __restrict__ ab,
    const float* __restrict__ vb, const float* __restrict__ decb,
    const float* __restrict__ k_k, const float* __restrict__ k_a,
    float* __restrict__ Gb, float* __restrict__ Ub,
    float* __restrict__ Bpb, float* __restrict__ Kpb,
    float* __restrict__ wcb, int cb)
{
    __shared__ __align__(16) float sA[64 * STR];   // ApT -> Yk -> Tinv
    __shared__ __align__(16) float sO[64 * STR];   // BpT -> KpT -> YkV
    __shared__ __align__(16) float sT[64 * STR];   // X
    __shared__ float sSeg[4][64];
    const int inst = blockIdx.x;
    const int bhd = inst / CBT, lc = inst % CBT;
    const int dir = bhd & 1, bh = bhd >> 1, b = bh >> 4, h = bh & 15;
    const int c64 = (cb * CBT + lc) * LCH;
    const int tid = threadIdx.x;
    const int lane = tid & 63, seg = tid >> 6;
    const int ch = h * 64 + lane;
    const size_t gbase = (size_t)inst * 4096;

    float loc[16];
    {
        float run = 1.f;
        #pragma unroll
        for (int i = 0; i < 16; i++) {
            int p = seg * 16 + i;
            int t = dir ? (TMAX - (c64 + p)) : (c64 + p);
            float d = decb[((size_t)(b * TT + t)) * CC + ch];
            run *= d; loc[i] = run;
        }
        sSeg[seg][lane] = run;
    }
    __syncthreads();
    float pre = 1.f;
    for (int s2 = 0; s2 < seg; ++s2) pre *= sSeg[s2][lane];
    float kreg[16];
    {
        const float kkl = k_k[ch], kal = k_a[ch];
        #pragma unroll
        for (int i = 0; i < 16; i++) {
            int p = seg * 16 + i;
            int t = dir ? (TMAX - (c64 + p)) : (c64 + p);
            size_t ra = ((size_t)(b * TT + t)) * CC + ch;
            float kraw = kb[ra], asig = ab[ra];
            float kkv = kraw * kkl;
            float s2 = waveReduceSum(kkv * kkv);
            float kkn = kkv / fmaxf(sqrtf(s2), 1e-12f);
            float wc = loc[i] * pre;
            float wx = (i == 0) ? pre : loc[i - 1] * pre;
            float apv = -kkn * wx;
            float bpv = kkn * asig / wc;
            float kpv = kraw * (1.f + (asig - 1.f) * kal) / wc;
            sA[lane * STR + p] = apv;
            sO[lane * STR + p] = bpv;
            kreg[i] = kpv;
            Gb[gbase + p * 64 + lane] = apv;      // Ap spill (row-major [p][ch])
            Bpb[gbase + p * 64 + lane] = bpv;
            Kpb[gbase + p * 64 + lane] = kpv;
            wcb[gbase + p * 64 + lane] = wc;
        }
    }
    __syncthreads();

    const int tr = (tid >> 4) * 4, tc = (tid & 15) * 4;
    // X = tril(Ap @ Bp^T, -1) -> sT
    {
        float acc[4][4] = {};
        gemm64<1, STR, 1, STR>(sA, sO, acc, tr, tc);
        #pragma unroll
        for (int r = 0; r < 4; r++)
            #pragma unroll
            for (int cq = 0; cq < 4; cq++)
                sT[(tr + r) * STR + tc + cq] = (tc + cq < tr + r) ? acc[r][cq] : 0.f;
    }
    __syncthreads();
    // sO <- KpT (from registers)
    #pragma unroll
    for (int i = 0; i < 16; i++)
        sO[lane * STR + seg * 16 + i] = kreg[i];
    __syncthreads();
    // Yk = tril(Ap @ Kp^T, -1) -> regs -> sA
    {
        float acc[4][4] = {};
        gemm64<1, STR, 1, STR>(sA, sO, acc, tr, tc);
        __syncthreads();
        #pragma unroll
        for (int r = 0; r < 4; r++)
            #pragma unroll
            for (int cq = 0; cq < 4; cq++)
                sA[(tr + r) * STR + tc + cq] = (tc + cq < tr + r) ? acc[r][cq] : 0.f;
    }
    __syncthreads();
    // YkV = Yk(sA) @ V(global) -> sO
    {
        float accY[4][4] = {};
        const float* vbase = vb + ((size_t)(b * TT + (dir ? (TMAX - c64) : c64))) * CC
                           + h * 64 + tc;
        const ptrdiff_t vstep = dir ? -(ptrdiff_t)CC : (ptrdiff_t)CC;
        #pragma unroll 2
        for (int j4 = 0; j4 < 64; j4 += 4) {
            float a_[4][4];
            #pragma unroll
            for (int r = 0; r < 4; r++) {
                float4 t4 = *(const float4*)&sA[(tr + r) * STR + j4];
                a_[r][0] = t4.x; a_[r][1] = t4.y; a_[r][2] = t4.z; a_[r][3] = t4.w;
            }
            float4 vq[4];
            #pragma unroll
            for (int kk = 0; kk < 4; kk++)
                vq[kk] = *(const float4*)(vbase + (ptrdiff_t)(j4 + kk) * vstep);
            #pragma unroll
            for (int r = 0; r < 4; r++) {
                accY[r][0] = fmaf(a_[r][0], vq[0].x, fmaf(a_[r][1], vq[1].x,
                             fmaf(a_[r][2], vq[2].x, fmaf(a_[r][3], vq[3].x, accY[r][0]))));
                accY[r][1] = fmaf(a_[r][0], vq[0].y, fmaf(a_[r][1], vq[1].y,
                             fmaf(a_[r][2], vq[2].y, fmaf(a_[r][3], vq[3].y, accY[r][1]))));
                accY[r][2] = fmaf(a_[r][0], vq[0].z, fmaf(a_[r][1], vq[1].z,
                             fmaf(a_[r][2], vq[2].z, fmaf(a_[r][3], vq[3].z, accY[r][2]))));
                accY[r][3] = fmaf(a_[r][0], vq[0].w, fmaf(a_[r][1], vq[1].w,
                             fmaf(a_[r][2], vq[2].w, fmaf(a_[r][3], vq[3].w, accY[r][3]))));
            }
        }
        __syncthreads();
        #pragma unroll
        for (int r = 0; r < 4; r++)
            #pragma unroll
            for (int cq = 0; cq < 4; cq++)
                sO[(tr + r) * STR + tc + cq] = accY[r][cq];
    }
    __syncthreads();
    // Tinv = (I - X)^{-1} -> sA. Column kept in registers; only the broadcast
    // sT row is read from LDS. 2-accumulator ILP halves the dependent chain.
    if (tid < 64) {
        float y[64];
        #pragma unroll
        for (int r = 0; r < 64; ++r) {
            float a0 = 0.f, a1 = 0.f;
            #pragma unroll
            for (int s = 0; s + 1 < r; s += 2) {
                a0 = fmaf(sT[r * STR + s],     y[s],     a0);
                a1 = fmaf(sT[r * STR + s + 1], y[s + 1], a1);
            }
            if (r & 1)
                a0 = fmaf(sT[r * STR + (r - 1)], y[r - 1], a0);
            y[r] = (r == tid) ? 1.f : (a0 + a1);
        }
        #pragma unroll
        for (int r = 0; r < 64; ++r)
            sA[r * STR + tid] = y[r];
    }
    __syncthreads();
    // U0 = Tinv @ YkV ; G = Tinv @ Ap(Gb)
    {
        float accU[4][4] = {};
        gemm64<STR, 1, 1, STR>(sA, sO, accU, tr, tc);
        float accG[4][4] = {};
        gemm64<STR, 1, 1, 64>(sA, Gb + gbase, accG, tr, tc);
        __syncthreads();
        #pragma unroll
        for (int r = 0; r < 4; r++) {
            *(float4*)&Gb[gbase + (tr + r) * 64 + tc] =
                make_float4(accG[r][0], accG[r][1], accG[r][2], accG[r][3]);
            *(float4*)&Ub[gbase + (tr + r) * 64 + tc] =
                make_float4(accU[r][0], accU[r][1], accU[r][2], accU[r][3]);
        }
    }
}

// ---------------------------------------------------------------------------
// wkvB v4 (round-20 form — passed): quarter decomposition, grid 512.
// ---------------------------------------------------------------------------
template<int CBT>
__global__ __launch_bounds__(256) void wkvB(
    const float* __restrict__ vb,
    const float* __restrict__ Gb, float* __restrict__ Ub,
    const float* __restrict__ Bpb, const float* __restrict__ Kpb,
    const float* __restrict__ wcb, float* __restrict__ S0b,
    float* __restrict__ Scur, int cb)
{
    __shared__ __align__(16) float sG[64 * STR];    // G[s][j]
    __shared__ __align__(16) float sB[64 * STR];    // Bp[s][j]
    __shared__ __align__(16) float sK[64 * STR];    // Kp[s][j]
    __shared__ __align__(16) float sS[16 * STR];    // S rows subset [i'][j]
    __shared__ __align__(16) float sU[64 * STR3];   // U[s][i']
    __shared__ __align__(16) float sV[64 * STR3];   // V[s][i']
    const int blk = blockIdx.x;
    const int bhd = blk >> 2, q = blk & 3;
    const int dir = bhd & 1, bh = bhd >> 1, b = bh >> 4, h = bh & 15;
    const int tid = threadIdx.x;
    const int i0 = q * 16;

    for (int i = tid; i < 1024; i += 256) {
        int rr = i >> 6, jj = i & 63;
        sS[rr * STR + jj] = Scur[(size_t)bhd * 4096 + (size_t)(i0 + rr) * 64 + jj];
    }
    __syncthreads();

    for (int lc = 0; lc < CBT; ++lc) {
        const int inst = bhd * CBT + lc;
        const size_t gbase = (size_t)inst * 4096;
        const int c64 = (cb * CBT + lc) * LCH;
        for (int i = tid; i < 4096; i += 256) {
            int rr = i >> 6, jj = i & 63;
            sG[rr * STR + jj] = Gb[gbase + i];
            sB[rr * STR + jj] = Bpb[gbase + i];
            sK[rr * STR + jj] = Kpb[gbase + i];
        }
        for (int i = tid; i < 1024; i += 256) {
            int s = i >> 4, ii = i & 15;
            int t = dir ? (TMAX - (c64 + s)) : (c64 + s);
            sV[s * STR3 + ii] = vb[((size_t)(b * TT + t)) * CC + h * 64 + i0 + ii];
        }
        for (int i = tid; i < 1024; i += 256) {
            int rr = i >> 6, jj = i & 63;
            S0b[gbase + (size_t)(i0 + rr) * 64 + jj] = sS[rr * STR + jj];
        }
        __syncthreads();
        // U[s][i'] = U0[s][i0+i'] + sum_j G[s][j] * S[i'][j]   (64x16, tile 4x1)
        {
            const int ts = (tid >> 4) * 4;
            const int ti = tid & 15;
            float acc[4];
            #pragma unroll
            for (int r = 0; r < 4; r++)
                acc[r] = Ub[gbase + (size_t)(ts + r) * 64 + i0 + ti];
            #pragma unroll 2
            for (int j4 = 0; j4 < 64; j4 += 4) {
                float4 g0 = *(const float4*)&sG[(ts + 0) * STR + j4];
                float4 g1 = *(const float4*)&sG[(ts + 1) * STR + j4];
                float4 g2 = *(const float4*)&sG[(ts + 2) * STR + j4];
                float4 g3 = *(const float4*)&sG[(ts + 3) * STR + j4];
                float4 sv = *(const float4*)&sS[ti * STR + j4];
                acc[0] = fmaf(g0.x,sv.x,fmaf(g0.y,sv.y,fmaf(g0.z,sv.z,fmaf(g0.w,sv.w,acc[0]))));
                acc[1] = fmaf(g1.x,sv.x,fmaf(g1.y,sv.y,fmaf(g1.z,sv.z,fmaf(g1.w,sv.w,acc[1]))));
                acc[2] = fmaf(g2.x,sv.x,fmaf(g2.y,sv.y,fmaf(g2.z,sv.z,fmaf(g2.w,sv.w,acc[2]))));
                acc[3] = fmaf(g3.x,sv.x,fmaf(g3.y,sv.y,fmaf(g3.z,sv.z,fmaf(g3.w,sv.w,acc[3]))));
            }
            #pragma unroll
            for (int r = 0; r < 4; r++) {
                sU[(ts + r) * STR3 + ti] = acc[r];
                Ub[gbase + (size_t)(ts + r) * 64 + i0 + ti] = acc[r];
            }
        }
        __syncthreads();
        // S'[i'][j] = (S + sum_s U[s][i']*Bp[s][j] + sum_s V[s][i']*Kp[s][j]) * w63[j]
        {
            const int ti = tid >> 4;             // 0..15 state row
            const int tj = (tid & 15) * 4;       // 64 cols
            float acc[4] = {};
            for (int s = 0; s < 64; ++s) {
                float u0 = sU[s * STR3 + ti];
                float v0 = sV[s * STR3 + ti];
                float4 bq = *(const float4*)&sB[s * STR + tj];
                float4 kq = *(const float4*)&sK[s * STR + tj];
                acc[0] = fmaf(u0, bq.x, fmaf(v0, kq.x, acc[0]));
                acc[1] = fmaf(u0, bq.y, fmaf(v0, kq.y, acc[1]));
                acc[2] = fmaf(u0, bq.z, fmaf(v0, kq.z, acc[2]));
                acc[3] = fmaf(u0, bq.w, fmaf(v0, kq.w, acc[3]));
            }
            float w63[4];
            #pragma unroll
            for (int cq = 0; cq < 4; cq++)
                w63[cq] = wcb[gbase + 63 * 64 + tj + cq];
            #pragma unroll
            for (int cq = 0; cq < 4; cq++) {
                float sv = sS[ti * STR + tj + cq];
                sS[ti * STR + tj + cq] = (sv + acc[cq]) * w63[cq];
            }
        }
        __syncthreads();
    }
    for (int i = tid; i < 1024; i += 256)
        Scur[(size_t)bhd * 4096 + (size_t)(i0 + (i >> 6)) * 64 + (i & 63)]
            = sS[(i >> 6) * STR + (i & 63)];
}

// ---------------------------------------------------------------------------
// wkvC (round-20 form — passed; no launch-bounds min, avoids VGPR spills)
// ---------------------------------------------------------------------------
template<int CBT>
__global__ __launch_bounds__(256) void wkvC(
    const float* __restrict__ rb, const float* __restrict__ vb,
    const float* __restrict__ Bpb, const float* __restrict__ Kpb,
    const float* __restrict__ Ub, const float* __restrict__ S0b,
    const float* __restrict__ wcb, const float* __restrict__ alpha_p,
    float* __restrict__ yb, int cb)
{
    __shared__ __align__(16) float sR[64 * STR];
    __shared__ __align__(16) float sO[64 * STR];
    __shared__ __align__(16) float sT2[64 * STR];
    const int inst = blockIdx.x;
    const int bhd = inst / CBT, lc = inst % CBT;
    const int dir = bhd & 1, bh = bhd >> 1, b = bh >> 4, h = bh & 15;
    const int c64 = (cb * CBT + lc) * LCH;
    const int tid = threadIdx.x, lane = tid & 63, seg = tid >> 6;
    const size_t gbase = (size_t)inst * 4096;
    const float alpha = alpha_p[0];
    const float wscale = dir ? (1.f - alpha) : alpha;
    const bool first = (cb < (32 / CBT));

    #pragma unroll
    for (int i = 0; i < 16; i++) {
        int p = seg * 16 + i;
        int t = dir ? (TMAX - (c64 + p)) : (c64 + p);
        size_t ra = ((size_t)(b * TT + t)) * CC + h * 64 + lane;
        float wc = wcb[gbase + p * 64 + lane];
        sR[lane * STR + p] = rb[ra] * wc;
        sO[lane * STR + p] = Bpb[gbase + p * 64 + lane];
    }
    __syncthreads();
    const int tr = (tid >> 4) * 4, tc = (tid & 15) * 4;
    float accO[4][4] = {};
    {
        float acc[4][4] = {};
        gemm64<1, STR, 1, STR>(sR, sO, acc, tr, tc);
        #pragma unroll
        for (int r = 0; r < 4; r++)
            #pragma unroll
            for (int cq = 0; cq < 4; cq++)
                sT2[(tr + r) * STR + tc + cq] = (tc + cq <= tr + r) ? acc[r][cq] : 0.f;
    }
    __syncthreads();
    for (int i = tid; i < 4096; i += 256)
        sO[(i >> 6) * STR + (i & 63)] = Ub[gbase + i];
    __syncthreads();
    gemm64<STR, 1, 1, STR>(sT2, sO, accO, tr, tc);
    __syncthreads();
    #pragma unroll
    for (int i = 0; i < 16; i++) {
        int p = seg * 16 + i;
        sO[lane * STR + p] = Kpb[gbase + p * 64 + lane];
    }
    __syncthreads();
    {
        float acc[4][4] = {};
        gemm64<1, STR, 1, STR>(sR, sO, acc, tr, tc);
        #pragma unroll
        for (int r = 0; r < 4; r++)
            #pragma unroll
            for (int cq = 0; cq < 4; cq++)
                sT2[(tr + r) * STR + tc + cq] = (tc + cq <= tr + r) ? acc[r][cq] : 0.f;
    }
    __syncthreads();
    #pragma unroll
    for (int i = 0; i < 16; i++) {
        int p = seg * 16 + i;
        int t = dir ? (TMAX - (c64 + p)) : (c64 + p);
        sO[p * STR + lane] = vb[((size_t)(b * TT + t)) * CC + h * 64 + lane];
    }
    __syncthreads();
    gemm64<STR, 1, 1, STR>(sT2, sO, accO, tr, tc);
    __syncthreads();
    for (int i = tid; i < 4096; i += 256)
        sO[(i >> 6) * STR + (i & 63)] = S0b[gbase + i];
    __syncthreads();
    gemm64<1, STR, STR, 1>(sR, sO, accO, tr, tc);
    #pragma unroll
    for (int r = 0; r < 4; r++) {
        int p = tr + r;
        int t = dir ? (TMAX - (c64 + p)) : (c64 + p);
        float* yp = &yb[((size_t)(b * TT + t)) * CC + h * 64 + tc];
        float4 o;
        if (first) {
            o.x = wscale * accO[r][0];
            o.y = wscale * accO[r][1];
            o.z = wscale * accO[r][2];
            o.w = wscale * accO[r][3];
        } else {
            float4 old = *(float4*)yp;
            o.x = old.x + wscale * accO[r][0];
            o.y = old.y + wscale * accO[r][1];
            o.z = old.z + wscale * accO[r][2];
            o.w = old.w + wscale * accO[r][3];
        }
        *(float4*)yp = o;
    }
}

// ---------------------------------------------------------------------------
// Post: GroupNorm + affine + bonus + gating; emits z as split bf16 (hi+lo)
// AND copies v_first into the output's second half (fuses the D2D memcpy:
// each thread reads its yb element first, then overwrites it with v_first).
// ---------------------------------------------------------------------------
__global__ __launch_bounds__(256) void post_kernel(
    const float* __restrict__ yb, const float* __restrict__ rbv,
    const float* __restrict__ kbv, const float* __restrict__ abv,
    const float* __restrict__ vbv, const float* __restrict__ gbv,
    const float* __restrict__ kaw, const float* __restrict__ r_k,
    const float* __restrict__ ln_w, const float* __restrict__ ln_b,
    const float* __restrict__ vfirst, float* __restrict__ vout,
    unsigned short* __restrict__ zh, unsigned short* __restrict__ zl)
{
    const int t = blockIdx.x;
    const int tid = threadIdx.x;
    const size_t base = (size_t)t * CC;
    #pragma unroll
    for (int j = 0; j < 4; j++) {
        int c = tid + 256 * j;
        float y = yb[base + c];
        float s1 = waveReduceSum(y);
        float s2 = waveReduceSum(y * y);
        float mu = s1 * (1.0f / 64.0f);
        float var = s2 * (1.0f / 64.0f) - mu * mu;
        float yn = (y - mu) * rsqrtf(var + EPS_GN);
        yn = yn * ln_w[c] + ln_b[c];
        float rv = rbv[base + c];
        float kf = kbv[base + c] * (1.0f + (abv[base + c] - 1.0f) * kaw[c]);
        float vv = vbv[base + c];
        float dot = waveReduceSum(rv * kf * r_k[c]);
        yn += dot * vv;
        float z = yn * gbv[base + c];
        unsigned short h = f2bf(z);
        zh[base + c] = h;
        zl[base + c] = f2bf(z - bf2f(h));
        vout[base + c] = vfirst[base + c];   // v_first passthrough (yb dead now)
    }
}

// ---------------------------------------------------------------------------
extern "C" void kernel_launch(void* const* d_in, const int* in_sizes, int n_in,
                              void* d_out, int out_size, void* d_ws, size_t ws_size,
                              hipStream_t stream)
{
    (void)in_sizes; (void)n_in; (void)out_size;
    const float* x      = (const float*)d_in[0];
    const float* vfirst = (const float*)d_in[1];
    const float* x_r    = (const float*)d_in[2];
    const float* x_w    = (const float*)d_in[3];
    const float* x_k    = (const float*)d_in[4];
    const float* x_v    = (const float*)d_in[5];
    const float* x_a    = (const float*)d_in[6];
    const float* x_g    = (const float*)d_in[7];
    const float* w0     = (const float*)d_in[8];
    const float* w1     = (const float*)d_in[9];
    const float* w2     = (const float*)d_in[10];
    const float* a0     = (const float*)d_in[11];
    const float* a1     = (const float*)d_in[12];
    const float* a2     = (const float*)d_in[13];
    const float* v0     = (const float*)d_in[14];
    const float* v1     = (const float*)d_in[15];
    const float* v2     = (const float*)d_in[16];
    const float* g1     = (const float*)d_in[17];
    const float* g2     = (const float*)d_in[18];
    const float* k_k    = (const float*)d_in[19];
    const float* k_a    = (const float*)d_in[20];
    const float* r_k    = (const float*)d_in[21];
    const float* Wr     = (const float*)d_in[22];
    const float* Wk     = (const float*)d_in[23];
    const float* Wv     = (const float*)d_in[24];
    const float* Wo     = (const float*)d_in[25];
    const float* ln_w   = (const float*)d_in[26];
    const float* ln_b   = (const float*)d_in[27];
    const float* alpha  = (const float*)d_in[28];

    // big path: CBT=16 chunks/batch needs ~584 MB workspace
    const bool big = (ws_size >= 600ull * 1000 * 1000);
    const size_t CHB = (size_t)128 * (big ? 16 : 8) * 4096;

    const size_t SZ = (size_t)BT * CC;
    float* ws   = (float*)d_ws;
    float* rb   = ws + 0 * SZ;
    float* kb   = ws + 1 * SZ;
    float* vb   = ws + 2 * SZ;
    float* decb = ws + 3 * SZ;
    float* ab   = ws + 4 * SZ;
    float* actf = ws + 5 * SZ;
    unsigned short* awh = (unsigned short*)actf;
    unsigned short* awl = awh + (size_t)BT * 64;
    unsigned short* aah = awl + (size_t)BT * 64;
    unsigned short* aal = aah + (size_t)BT * 64;
    unsigned short* avh = aal + (size_t)BT * 64;
    unsigned short* avl = avh + (size_t)BT * 64;
    unsigned short* agh = avl + (size_t)BT * 64;
    unsigned short* agl = agh + (size_t)BT * 192;
    float* Gb   = actf + (size_t)BT * 384;
    float* Ub   = Gb + CHB;
    float* Bpb  = Ub + CHB;
    float* Kpb  = Bpb + CHB;
    float* S0b  = Kpb + CHB;
    float* wcb  = S0b + CHB;
    float* Scur = wcb + CHB;
    unsigned short* W4h = (unsigned short*)(Scur + (size_t)128 * 4096);
    unsigned short* W4l = W4h + (size_t)CC * CC * 4;
    unsigned short* w2th = W4l + (size_t)CC * CC * 4;
    unsigned short* w2tl = w2th + (size_t)CC * 64;
    unsigned short* a2th = w2tl + (size_t)CC * 64;
    unsigned short* a2tl = a2th + (size_t)CC * 64;
    unsigned short* v2th = a2tl + (size_t)CC * 64;
    unsigned short* v2tl = v2th + (size_t)CC * 64;
    unsigned short* g2th = v2tl + (size_t)CC * 64;
    unsigned short* g2tl = g2th + (size_t)CC * 192;
    // stage-1 weight splits (transposed, Npad rows x 1024)
    unsigned short* w1th = g2tl + (size_t)CC * 192;
    unsigned short* w1tl = w1th + (size_t)64 * CC;
    unsigned short* a1th = w1tl + (size_t)64 * CC;
    unsigned short* a1tl = a1th + (size_t)64 * CC;
    unsigned short* v1th = a1tl + (size_t)64 * CC;
    unsigned short* v1tl = v1th + (size_t)64 * CC;
    unsigned short* g1th = v1tl + (size_t)64 * CC;
    unsigned short* g1tl = g1th + (size_t)192 * CC;
    float* outp = (float*)d_out;
    unsigned short* xrh = (unsigned short*)outp;          // [0, SZ) ushorts
    unsigned short* xrl = xrh + SZ;
    unsigned short* xkh = xrl + SZ;
    unsigned short* xkl = xkh + SZ;
    unsigned short* xvh = (unsigned short*)decb;
    unsigned short* xvl = xvh + SZ;
    unsigned short* xwh = (unsigned short*)rb;            // dead until proj gemm
    unsigned short* xwl = xwh + SZ;
    unsigned short* xah = (unsigned short*)kb;
    unsigned short* xal = xah + SZ;
    unsigned short* xgh = (unsigned short*)vb;
    unsigned short* xgl = xgh + SZ;
    float* gb   = outp;
    float* yb   = outp + SZ;
    unsigned short* zAh = (unsigned short*)decb;
    unsigned short* zAl = zAh + SZ;

    dim3 blk(256);
    const int NG_A = BT * (CC / 8);
    dim3 gridA(NG_A / 256);

    // fused x-mix split (all 6 mixes) — reads x once
    conv_split_x6<<<gridA, blk, 0, stream>>>(x, x_r, x_k, x_v, x_w, x_a, x_g,
        xrh, xrl, xkh, xkl, xvh, xvl, xwh, xwl, xah, xal, xgh, xgl);
    // weight conversions (merged: 1 + 1 + 1 launches)
    conv_w4<<<dim3(512, 4), blk, 0, stream>>>(Wr, Wk, Wv, Wo, W4h, W4l);
    conv_w1y<<<dim3(96, 4), blk, 0, stream>>>(w1, a1, v1, g1,
        w1th, w1tl, a1th, a1tl, v1th, v1tl, g1th, g1tl);
    conv_w2y<<<dim3(96, 4), blk, 0, stream>>>(w2, a2, v2, g2,
        w2th, w2tl, a2th, a2tl, v2th, v2tl, g2th, g2tl);

    // LoRA stage-1 on MFMA (must run BEFORE proj gemm overwrites rb/kb/vb)
    lora1_mfma<<<dim3(BT / 128, 6), blk, 0, stream>>>(
        xwh, xwl, xah, xal, xvh, xvl, xgh, xgl,
        w1th, w1tl, a1th, a1tl, v1th, v1tl, g1th, g1tl,
        awh, awl, aah, aal, avh, avl, agh, agl);

    // r, k, v projections in ONE launch (sel via blockIdx.y; W slots 0..2)
    gemm_split_bf16<<<dim3(1024, 3), blk, 0, stream>>>(
        xrh, xrl, xkh, xkl, xvh, xvl, W4h, W4l, rb, kb, vb, 0);

    // LoRA stage-2 on MFMA (writes decb over xv pair — dead after proj gemm)
    lora2_mfma<<<dim3(BT / 128, CC / 64, 4), blk, 0, stream>>>(
        awh, awl, aah, aal, avh, avl, agh, agl,
        w2th, w2tl, a2th, a2tl, v2th, v2tl, g2th, g2tl,
        w0, a0, v0, vfirst, decb, ab, vb, gb);

    // chunked bidirectional WKV
    hipMemsetAsync(Scur, 0, (size_t)128 * 4096 * sizeof(float), stream);
    if (big) {
        for (int cb = 0; cb < 4; ++cb) {
            wkvA<16><<<dim3(2048), blk, 0, stream>>>(kb, ab, vb, decb, k_k, k_a,
                                                     Gb, Ub, Bpb, Kpb, wcb, cb);
            wkvB<16><<<dim3(512), blk, 0, stream>>>(vb, Gb, Ub, Bpb, Kpb, wcb,
                                                    S0b, Scur, cb);
            wkvC<16><<<dim3(2048), blk, 0, stream>>>(rb, vb, Bpb, Kpb, Ub, S0b,
                                                     wcb, alpha, yb, cb);
        }
    } else {
        for (int cb = 0; cb < 8; ++cb) {
            wkvA<8><<<dim3(1024), blk, 0, stream>>>(kb, ab, vb, decb, k_k, k_a,
                                                    Gb, Ub, Bpb, Kpb, wcb, cb);
            wkvB<8><<<dim3(512), blk, 0, stream>>>(vb, Gb, Ub, Bpb, Kpb, wcb,
                                                   S0b, Scur, cb);
            wkvC<8><<<dim3(1024), blk, 0, stream>>>(rb, vb, Bpb, Kpb, Ub, S0b,
                                                    wcb, alpha, yb, cb);
        }
    }

    // groupnorm + bonus + gate -> split bf16 z; also v_first passthrough
    post_kernel<<<dim3(BT), blk, 0, stream>>>(yb, rb, kb, ab, vb, gb, k_a, r_k,
                                              ln_w, ln_b, vfirst, yb, zAh, zAl);
    // final projection (W slot 3 = Wo)
    gemm_split_bf16<<<dim3(1024, 1), blk, 0, stream>>>(
        zAh, zAl, zAh, zAl, zAh, zAl, W4h, W4l, outp, outp, outp, 3);
}